// Round 3
// baseline (85005.151 us; speedup 1.0000x reference)
//
#include <hip/hip_runtime.h>
#include <hip/hip_fp16.h>

typedef float f32x4 __attribute__((ext_vector_type(4)));
typedef _Float16 half8 __attribute__((ext_vector_type(8)));
typedef _Float16 half2t __attribute__((ext_vector_type(2)));
typedef unsigned int u32;

#define DEVI static __device__ __forceinline__

constexpr int BATCH = 32;
constexpr int TLEN  = 2048;
constexpr int HDIM  = 512;
constexpr int G3    = 1536;   // 3*H

DEVI float fast_sigmoid(float x) { return 1.0f / (1.0f + __expf(-x)); }

DEVI u32 pack2h(float a, float b) {
#if __has_builtin(__builtin_amdgcn_cvt_pkrtz)
  return __builtin_bit_cast(u32, __builtin_amdgcn_cvt_pkrtz(a, b));
#else
  half2t h; h.x = (_Float16)a; h.y = (_Float16)b;
  return __builtin_bit_cast(u32, h);
#endif
}

DEVI float dot2acc(u32 w, u32 h, float acc) {
#if __has_builtin(__builtin_amdgcn_fdot2)
  return __builtin_amdgcn_fdot2(__builtin_bit_cast(half2t, w),
                                __builtin_bit_cast(half2t, h), acc, false);
#else
  half2t a = __builtin_bit_cast(half2t, w);
  half2t b = __builtin_bit_cast(half2t, h);
  return acc + (float)a.x * (float)b.x + (float)a.y * (float)b.y;
#endif
}

DEVI float llc_loadf(const float* p) {
  return __hip_atomic_load(p, __ATOMIC_RELAXED, __HIP_MEMORY_SCOPE_AGENT);
}
DEVI void llc_storef(float* p, float v) {
  __hip_atomic_store(p, v, __ATOMIC_RELAXED, __HIP_MEMORY_SCOPE_AGENT);
}

// ---------------- weight conversion (fp32 -> fp16) ----------------
__global__ void convert_weights(const float* __restrict__ wih, const float* __restrict__ whh,
                                _Float16* __restrict__ wih_h, _Float16* __restrict__ whh_h)
{
  const size_t n = (size_t)2 * G3 * HDIM;
  for (size_t i = (size_t)blockIdx.x * blockDim.x + threadIdx.x; i < n;
       i += (size_t)gridDim.x * blockDim.x) {
    wih_h[i] = (_Float16)wih[i];
    whh_h[i] = (_Float16)whh[i];
  }
}

// ---------------- layernorm: fp32 in -> fp16 out ----------------
__global__ __launch_bounds__(256) void ln_kernel(const float* __restrict__ x,
    const float* __restrict__ gamma, const float* __restrict__ beta,
    _Float16* __restrict__ out)
{
  const int row = blockIdx.x;
  const int tid = threadIdx.x;
  const float* xr = x + (size_t)row * HDIM;
  float a = xr[tid], b = xr[tid + 256];
  float s = a + b, ss = a * a + b * b;
#pragma unroll
  for (int m = 1; m < 64; m <<= 1) {
    s  += __shfl_xor(s, m, 64);
    ss += __shfl_xor(ss, m, 64);
  }
  __shared__ float sb[8];
  const int w = tid >> 6;
  if ((tid & 63) == 0) { sb[w] = s; sb[4 + w] = ss; }
  __syncthreads();
  s  = sb[0] + sb[1] + sb[2] + sb[3];
  ss = sb[4] + sb[5] + sb[6] + sb[7];
  const float mu   = s * (1.0f / HDIM);
  const float var  = ss * (1.0f / HDIM) - mu * mu;
  const float rstd = rsqrtf(var + 1e-5f);
  out[(size_t)row * HDIM + tid]       = (_Float16)((a - mu) * rstd * gamma[tid] + beta[tid]);
  out[(size_t)row * HDIM + tid + 256] = (_Float16)((b - mu) * rstd * gamma[tid + 256] + beta[tid + 256]);
}

// ---------------- fp16 MFMA GEMM: C[m,n] = sum_k A[m,k]*W[n,k] + bias[n] ----------------
__global__ __launch_bounds__(256) void gemm_f16(
    const _Float16* __restrict__ A, const _Float16* __restrict__ W,
    const float* __restrict__ bias, _Float16* __restrict__ C,
    int t0, int lgT)
{
  __shared__ _Float16 As[128][40];
  __shared__ _Float16 Bs[128][40];
  const int bm = blockIdx.x;
  const int bn = blockIdx.y;
  const int tid = threadIdx.x;
  const int lane = tid & 63;
  const int wv = tid >> 6;
  const int wm = wv >> 1, wn = wv & 1;
  const int l15 = lane & 15, g4 = lane >> 4;
  const int tmask = (1 << lgT) - 1;

  f32x4 zero4 = {0.f, 0.f, 0.f, 0.f};
  f32x4 acc[4][4];
#pragma unroll
  for (int i = 0; i < 4; ++i) {
#pragma unroll
    for (int j = 0; j < 4; ++j) acc[i][j] = zero4;
  }

  const int srow = tid >> 2;
  const int scol = (tid & 3) * 8;
  size_t arow[2];
#pragma unroll
  for (int r2 = 0; r2 < 2; ++r2) {
    int m = bm * 128 + r2 * 64 + srow;
    int b = m >> lgT, tt = m & tmask;
    arow[r2] = ((size_t)b * TLEN + (size_t)(t0 + tt)) * HDIM;
  }
  const size_t brow0 = (size_t)(bn * 128 + srow) * HDIM;

  for (int kt = 0; kt < HDIM; kt += 32) {
#pragma unroll
    for (int r2 = 0; r2 < 2; ++r2) {
      *(uint4*)&As[r2 * 64 + srow][scol] = *(const uint4*)&A[arow[r2] + kt + scol];
      *(uint4*)&Bs[r2 * 64 + srow][scol] = *(const uint4*)&W[brow0 + (size_t)r2 * 64 * HDIM + kt + scol];
    }
    __syncthreads();
    half8 af[4], bf[4];
#pragma unroll
    for (int i = 0; i < 4; ++i) af[i] = *(const half8*)&As[wm * 64 + i * 16 + l15][g4 * 8];
#pragma unroll
    for (int j = 0; j < 4; ++j) bf[j] = *(const half8*)&Bs[wn * 64 + j * 16 + l15][g4 * 8];
#pragma unroll
    for (int i = 0; i < 4; ++i) {
#pragma unroll
      for (int j = 0; j < 4; ++j)
        acc[i][j] = __builtin_amdgcn_mfma_f32_16x16x32_f16(af[i], bf[j], acc[i][j], 0, 0, 0);
    }
    __syncthreads();
  }
#pragma unroll
  for (int j = 0; j < 4; ++j) {
    const int col = bn * 128 + wn * 64 + j * 16 + l15;
    const float bi = bias[col];
#pragma unroll
    for (int i = 0; i < 4; ++i) {
      const int mrow = bm * 128 + wm * 64 + i * 16 + g4 * 4;
#pragma unroll
      for (int r = 0; r < 4; ++r)
        C[(size_t)(mrow + r) * G3 + col] = (_Float16)(acc[i][j][r] + bi);
    }
  }
}

// ---------------- sync-state init ----------------
__global__ void init_sync(float* __restrict__ hbuf, u32* __restrict__ flags)
{
  const int i = blockIdx.x * 256 + threadIdx.x;
  if (i < 2 * BATCH * HDIM) hbuf[i] = 0.0f;
  if (i < BATCH * 64) flags[i] = 0u;
}

DEVI void store_out(_Float16* p, float v) { *p = (_Float16)v; }
DEVI void store_out(float* p, float v)    { *p = v; }

// ---------------- persistent GRU recurrence (barrier-free, wave-granular) ----------------
// grid = 256 blocks: g = bid&31 (batch), c = bid>>5 (dim chunk of 64).
// XCD affinity: all 8 chunks of group g share bid%8 == g%8.
// Per-wave flags[g][c*8+w]: wave publishes after its own vmcnt drain; consumers poll
// all 64 flags with one 64-lane load + __all. No __syncthreads / fences in the loop.
template <typename OUT_T>
__global__ __launch_bounds__(512, 2) void gru_rec(
    const _Float16* __restrict__ xp,   // [BATCH][TSEG][G3]
    const u32* __restrict__ whh,       // [G3][HDIM] fp16 as u32 pairs
    const float* __restrict__ bhh,     // [G3]
    OUT_T* __restrict__ hout,          // [BATCH][TLEN][HDIM]
    float* __restrict__ hbuf,          // [2][BATCH][HDIM]
    u32* __restrict__ flags,           // [BATCH][64]
    int t0, int t1, int lgT)
{
  const int g = blockIdx.x & 31;
  const int c = blockIdx.x >> 5;
  const int tid = threadIdx.x;
  const int q = tid >> 4;       // 0..31
  const int l16 = tid & 15;
  const int lane = tid & 63;
  const int w = tid >> 6;       // wave 0..7

  u32 wp[6][16];
  float bh[6];
#pragma unroll
  for (int p = 0; p < 6; ++p) {
    const int row = (p >> 1) * 512 + c * 64 + ((p & 1) << 5) + q;  // gate-major rows r,z,n
    const uint4* src = (const uint4*)(whh + (size_t)row * 256 + l16 * 16);
#pragma unroll
    for (int v = 0; v < 4; ++v) {
      uint4 u = src[v];
      wp[p][v * 4 + 0] = u.x; wp[p][v * 4 + 1] = u.y;
      wp[p][v * 4 + 2] = u.z; wp[p][v * 4 + 3] = u.w;
    }
    bh[p] = bhh[row];
  }

  u32* const gf = flags + (g << 6);

  for (int t = t0; t < t1; ++t) {
    // prefetch xp for this step (normal cached loads; latency overlaps the poll)
    float xv[6];
    {
      const size_t xrow = ((size_t)(g << lgT) + (size_t)(t - t0)) * G3;
#pragma unroll
      for (int p = 0; p < 6; ++p) {
        const int col = (p >> 1) * 512 + c * 64 + ((p & 1) << 5) + q;
        xv[p] = (float)xp[xrow + col];
      }
    }
    // poll all 64 wave-flags of this group (one lane per flag)
    {
      const u32 tt = (u32)t;
      while (true) {
        u32 f = __hip_atomic_load(&gf[lane], __ATOMIC_RELAXED, __HIP_MEMORY_SCOPE_AGENT);
        if (__all((int)(f >= tt))) break;
        __builtin_amdgcn_s_sleep(1);
      }
    }
    // load h_t (LLC-bypassing; 16-lane broadcast coalesced), pack to fp16 pairs
    const float* hsrc = &hbuf[((size_t)(t & 1) * BATCH + g) * HDIM];
    u32 hp[16];
#pragma unroll
    for (int j = 0; j < 16; ++j) {
      float a = llc_loadf(&hsrc[l16 * 32 + 2 * j]);
      float b = llc_loadf(&hsrc[l16 * 32 + 2 * j + 1]);
      hp[j] = pack2h(a, b);
    }
    float hprev[2];
#pragma unroll
    for (int i = 0; i < 2; ++i)
      hprev[i] = llc_loadf(&hsrc[c * 64 + (i << 5) + q]);

    float acc[6];
#pragma unroll
    for (int p = 0; p < 6; ++p) {
      float s = 0.0f;
#pragma unroll
      for (int j = 0; j < 16; ++j) s = dot2acc(wp[p][j], hp[j], s);
      acc[p] = s;
    }
#pragma unroll
    for (int m = 1; m < 16; m <<= 1) {
#pragma unroll
      for (int p = 0; p < 6; ++p) acc[p] += __shfl_xor(acc[p], m, 64);
    }

    float hnew[2];
#pragma unroll
    for (int i = 0; i < 2; ++i) {
      const float r = fast_sigmoid(xv[i]     + acc[i]     + bh[i]);
      const float z = fast_sigmoid(xv[2 + i] + acc[2 + i] + bh[2 + i]);
      const float n = tanhf(xv[4 + i] + r * (acc[4 + i] + bh[4 + i]));
      hnew[i] = (1.0f - z) * n + z * hprev[i];
    }
    if (l16 == 0) {
#pragma unroll
      for (int i = 0; i < 2; ++i) {
        const int dg = c * 64 + (i << 5) + q;
        llc_storef(&hbuf[((size_t)((t + 1) & 1) * BATCH + g) * HDIM + dg], hnew[i]);
        store_out(&hout[((size_t)g * TLEN + t) * HDIM + dg], hnew[i]);
      }
    }
    // drain THIS wave's stores to the coherence point, then publish this wave's flag
    asm volatile("s_waitcnt vmcnt(0)" ::: "memory");
    if (lane == 0)
      __hip_atomic_store(&gf[(c << 3) + w], (u32)(t + 1),
                         __ATOMIC_RELAXED, __HIP_MEMORY_SCOPE_AGENT);
  }
}

// ---------------- host launcher ----------------
extern "C" void kernel_launch(void* const* d_in, const int* in_sizes, int n_in,
                              void* d_out, int out_size, void* d_ws, size_t ws_size,
                              hipStream_t stream)
{
  const float* x     = (const float*)d_in[0];
  const float* gamma = (const float*)d_in[1];
  const float* beta  = (const float*)d_in[2];
  const float* Wih   = (const float*)d_in[3];
  const float* Whh   = (const float*)d_in[4];
  const float* bih   = (const float*)d_in[5];
  const float* bhh   = (const float*)d_in[6];
  float* out = (float*)d_out;

  const size_t wbytes  = (size_t)2 * G3 * HDIM * 2;
  const size_t h1bytes = (size_t)BATCH * TLEN * HDIM * 2;
  const size_t fixed   = h1bytes + 2 * wbytes + (size_t)2 * BATCH * HDIM * 4
                       + (size_t)BATCH * 64 * 4 + 4096;
  int lgT = 11;
  while (lgT > 2 && ((size_t)BATCH * ((size_t)1 << lgT) * G3 * 2 + fixed) > ws_size) --lgT;
  const int TSEG = 1 << lgT;
  const int nseg = TLEN / TSEG;

  char* ws = (char*)d_ws;
  _Float16* xp    = (_Float16*)ws;
  char* base      = ws + (size_t)BATCH * TSEG * G3 * 2;
  _Float16* h1    = (_Float16*)base;
  _Float16* wih_h = (_Float16*)(base + h1bytes);
  _Float16* whh_h = (_Float16*)(base + h1bytes + wbytes);
  float*    hbuf  = (float*)   (base + h1bytes + 2 * wbytes);
  u32*      flags = (u32*)     (base + h1bytes + 2 * wbytes + (size_t)2 * BATCH * HDIM * 4);
  _Float16* hseq  = (_Float16*)d_out;   // LN output staging (fp16) — consumed before fp32 writes

  convert_weights<<<512, 256, 0, stream>>>(Wih, Whh, wih_h, whh_h);
  ln_kernel<<<BATCH * TLEN, 256, 0, stream>>>(x, gamma, beta, hseq);

  const dim3 ggrid(BATCH * TSEG / 128, 12);

  // layer 1
  init_sync<<<128, 256, 0, stream>>>(hbuf, flags);
  for (int s = 0; s < nseg; ++s) {
    const int t0 = s * TSEG;
    gemm_f16<<<ggrid, 256, 0, stream>>>(hseq, wih_h, bih, xp, t0, lgT);
    gru_rec<_Float16><<<256, 512, 0, stream>>>(xp, (const u32*)whh_h, bhh,
                                               h1, hbuf, flags, t0, t0 + TSEG, lgT);
  }
  // layer 2
  init_sync<<<128, 256, 0, stream>>>(hbuf, flags);
  for (int s = 0; s < nseg; ++s) {
    const int t0 = s * TSEG;
    gemm_f16<<<ggrid, 256, 0, stream>>>(h1, wih_h + (size_t)G3 * HDIM, bih + G3, xp, t0, lgT);
    gru_rec<float><<<256, 512, 0, stream>>>(xp, (const u32*)(whh_h + (size_t)G3 * HDIM), bhh + G3,
                                            out, hbuf, flags, t0, t0 + TSEG, lgT);
  }
}

// Round 5
// 33185.809 us; speedup vs baseline: 2.5615x; 2.5615x over previous
//
#include <hip/hip_runtime.h>
#include <hip/hip_fp16.h>

typedef float f32x4 __attribute__((ext_vector_type(4)));
typedef float f32x16 __attribute__((ext_vector_type(16)));
typedef _Float16 half8 __attribute__((ext_vector_type(8)));
typedef _Float16 half2t __attribute__((ext_vector_type(2)));
typedef unsigned int u32;

#define DEVI static __device__ __forceinline__

constexpr int BATCH = 32;
constexpr int TLEN  = 2048;
constexpr int HDIM  = 512;
constexpr int G3    = 1536;   // 3*H

DEVI float fast_sigmoid(float x) { return 1.0f / (1.0f + __expf(-x)); }

DEVI u32 pack2h(float a, float b) {
  return __builtin_bit_cast(u32, __builtin_amdgcn_cvt_pkrtz(a, b));
}

DEVI u32 llc_load32(const u32* p) {
  return __hip_atomic_load(p, __ATOMIC_RELAXED, __HIP_MEMORY_SCOPE_AGENT);
}
DEVI void llc_store32(u32* p, u32 v) {
  __hip_atomic_store(p, v, __ATOMIC_RELAXED, __HIP_MEMORY_SCOPE_AGENT);
}

// ---------------- weight conversion (fp32 -> fp16) ----------------
__global__ void convert_weights(const float* __restrict__ wih, const float* __restrict__ whh,
                                _Float16* __restrict__ wih_h, _Float16* __restrict__ whh_h)
{
  const size_t n = (size_t)2 * G3 * HDIM;
  for (size_t i = (size_t)blockIdx.x * blockDim.x + threadIdx.x; i < n;
       i += (size_t)gridDim.x * blockDim.x) {
    wih_h[i] = (_Float16)wih[i];
    whh_h[i] = (_Float16)whh[i];
  }
}

// ---------------- layernorm: fp32 in -> fp16 out ----------------
__global__ __launch_bounds__(256) void ln_kernel(const float* __restrict__ x,
    const float* __restrict__ gamma, const float* __restrict__ beta,
    _Float16* __restrict__ out)
{
  const int row = blockIdx.x;
  const int tid = threadIdx.x;
  const float* xr = x + (size_t)row * HDIM;
  float a = xr[tid], b = xr[tid + 256];
  float s = a + b, ss = a * a + b * b;
#pragma unroll
  for (int m = 1; m < 64; m <<= 1) {
    s  += __shfl_xor(s, m, 64);
    ss += __shfl_xor(ss, m, 64);
  }
  __shared__ float sb[8];
  const int w = tid >> 6;
  if ((tid & 63) == 0) { sb[w] = s; sb[4 + w] = ss; }
  __syncthreads();
  s  = sb[0] + sb[1] + sb[2] + sb[3];
  ss = sb[4] + sb[5] + sb[6] + sb[7];
  const float mu   = s * (1.0f / HDIM);
  const float var  = ss * (1.0f / HDIM) - mu * mu;
  const float rstd = rsqrtf(var + 1e-5f);
  out[(size_t)row * HDIM + tid]       = (_Float16)((a - mu) * rstd * gamma[tid] + beta[tid]);
  out[(size_t)row * HDIM + tid + 256] = (_Float16)((b - mu) * rstd * gamma[tid + 256] + beta[tid + 256]);
}

// ---------------- fp16 MFMA GEMM: C[m,n] = sum_k A[m,k]*W[n,k] + bias[n] ----------------
__global__ __launch_bounds__(256) void gemm_f16(
    const _Float16* __restrict__ A, const _Float16* __restrict__ W,
    const float* __restrict__ bias, _Float16* __restrict__ C,
    int t0, int lgT)
{
  __shared__ _Float16 As[128][40];
  __shared__ _Float16 Bs[128][40];
  const int bm = blockIdx.x;
  const int bn = blockIdx.y;
  const int tid = threadIdx.x;
  const int lane = tid & 63;
  const int wv = tid >> 6;
  const int wm = wv >> 1, wn = wv & 1;
  const int l15 = lane & 15, g4 = lane >> 4;
  const int tmask = (1 << lgT) - 1;

  f32x4 zero4 = {0.f, 0.f, 0.f, 0.f};
  f32x4 acc[4][4];
#pragma unroll
  for (int i = 0; i < 4; ++i) {
#pragma unroll
    for (int j = 0; j < 4; ++j) acc[i][j] = zero4;
  }

  const int srow = tid >> 2;
  const int scol = (tid & 3) * 8;
  size_t arow[2];
#pragma unroll
  for (int r2 = 0; r2 < 2; ++r2) {
    int m = bm * 128 + r2 * 64 + srow;
    int b = m >> lgT, tt = m & tmask;
    arow[r2] = ((size_t)b * TLEN + (size_t)(t0 + tt)) * HDIM;
  }
  const size_t brow0 = (size_t)(bn * 128 + srow) * HDIM;

  for (int kt = 0; kt < HDIM; kt += 32) {
#pragma unroll
    for (int r2 = 0; r2 < 2; ++r2) {
      *(uint4*)&As[r2 * 64 + srow][scol] = *(const uint4*)&A[arow[r2] + kt + scol];
      *(uint4*)&Bs[r2 * 64 + srow][scol] = *(const uint4*)&W[brow0 + (size_t)r2 * 64 * HDIM + kt + scol];
    }
    __syncthreads();
    half8 af[4], bf[4];
#pragma unroll
    for (int i = 0; i < 4; ++i) af[i] = *(const half8*)&As[wm * 64 + i * 16 + l15][g4 * 8];
#pragma unroll
    for (int j = 0; j < 4; ++j) bf[j] = *(const half8*)&Bs[wn * 64 + j * 16 + l15][g4 * 8];
#pragma unroll
    for (int i = 0; i < 4; ++i) {
#pragma unroll
      for (int j = 0; j < 4; ++j)
        acc[i][j] = __builtin_amdgcn_mfma_f32_16x16x32_f16(af[i], bf[j], acc[i][j], 0, 0, 0);
    }
    __syncthreads();
  }
#pragma unroll
  for (int j = 0; j < 4; ++j) {
    const int col = bn * 128 + wn * 64 + j * 16 + l15;
    const float bi = bias[col];
#pragma unroll
    for (int i = 0; i < 4; ++i) {
      const int mrow = bm * 128 + wm * 64 + i * 16 + g4 * 4;
#pragma unroll
      for (int r = 0; r < 4; ++r)
        C[(size_t)(mrow + r) * G3 + col] = (_Float16)(acc[i][j][r] + bi);
    }
  }
}

// ---------------- sync-state init ----------------
__global__ void init_sync(u32* __restrict__ hbuf, u32* __restrict__ flags)
{
  const int i = blockIdx.x * 256 + threadIdx.x;
  if (i < 2 * BATCH * 256) hbuf[i] = 0u;     // fp16 pairs (0,0)
  if (i < 64) flags[i] = 0u;
}

DEVI void store_out2(_Float16* p, float a, float b) { *(u32*)p = pack2h(a, b); }
DEVI void store_out2(float* p, float a, float b) { float2 v; v.x = a; v.y = b; *(float2*)p = v; }

// ---------------- persistent GRU recurrence: 8 blocks, MFMA over all 32 groups ----------------
// Block c owns output dims [c*64, c*64+64) (= 192 gate rows) for ALL 32 batch groups.
// Waves 0..5: one 32-row N-tile each via mfma_f32_32x32x16_f16, K=512 (32 steps),
// W_hh fragments persistent in 128 VGPRs. Waves 6,7 help with loads/epilogue only.
// h exchanged as fp16 pairs through LLC (agent-scope relaxed atomics); per-wave flags.
// NOTE: k-permutation of A/B fragments cancels (same mapping used for both operands);
// only the HW-verified C/D map matters.
template <typename OUT_T>
__global__ __launch_bounds__(512, 2) void gru_rec(
    const u32* __restrict__ xp,        // [BATCH][TSEG][768] u32 (fp16 pairs)
    const u32* __restrict__ whh,       // [G3][256] u32 (fp16 pairs)
    const float* __restrict__ bhh,     // [G3]
    OUT_T* __restrict__ hout,          // [BATCH][TLEN][HDIM]
    u32* __restrict__ hbuf,            // [2][32][256] u32
    u32* __restrict__ flags,           // [64] = [block 8][wave 8]
    int t0, int t1, int lgT)
{
  const int c = blockIdx.x;        // 0..7
  const int tid = threadIdx.x;
  const int lane = tid & 63;
  const int w = tid >> 6;
  const int l31 = lane & 31;
  const int kh = lane >> 5;        // K-half selector

  __shared__ u32  h_l[32 * 260];   // [group][260 u32] (+4 pad)
  __shared__ float sg[192 * 33];   // [local row][33 groups] (+1 pad)

  // persistent W_hh fragments (waves 0..5): B-operand, lane col = local row w*32+l31
  half8 bf[32];
  if (w < 6) {
    const int rl = w * 32 + l31;                               // 0..191
    const int grow = (rl >> 6) * 512 + c * 64 + (rl & 63);     // gate-major global row
#pragma unroll
    for (int ks = 0; ks < 32; ++ks)
      bf[ks] = *(const half8*)&whh[(size_t)grow * 256 + ks * 8 + kh * 4];
  }

  // epilogue mapping: thread -> dim pair (c*64+2dp, +1), groups {ga, ga+16}
  const int dp = tid & 31;
  const int ga = tid >> 5;
  float bias[3][2];
#pragma unroll
  for (int gt = 0; gt < 3; ++gt) {
    bias[gt][0] = bhh[gt * 512 + c * 64 + 2 * dp];
    bias[gt][1] = bhh[gt * 512 + c * 64 + 2 * dp + 1];
  }

  for (int t = t0; t < t1; ++t) {
    // prefetch xp (independent of sync; latency hides under poll)
    u32 xu[3][2];
    {
      const int tl = t - t0;
#pragma unroll
      for (int gi = 0; gi < 2; ++gi) {
        const size_t row = ((size_t)((ga + gi * 16) << lgT) + tl) * 768;
#pragma unroll
        for (int gt = 0; gt < 3; ++gt)
          xu[gt][gi] = xp[row + gt * 256 + c * 32 + dp];
      }
    }
    // poll all 64 wave-flags (one lane per flag)
    while (true) {
      u32 f = __hip_atomic_load(&flags[lane], __ATOMIC_RELAXED, __HIP_MEMORY_SCOPE_AGENT);
      if (__all((int)(f >= (u32)t))) break;
      __builtin_amdgcn_s_sleep(1);
    }
    // coalesced load h_t (32KB) -> LDS
    const u32* hsrc = hbuf + (size_t)(t & 1) * (BATCH * 256);
#pragma unroll
    for (int j = 0; j < 16; ++j) {
      const int i = j * 512 + tid;
      h_l[(i >> 8) * 260 + (i & 255)] = llc_load32(&hsrc[i]);
    }
    __syncthreads();   // B1

    // hprev for epilogue: this block's dims c*64+2dp (u32 col c*32+dp)
    const u32 hpa = h_l[ga * 260 + c * 32 + dp];
    const u32 hpb = h_l[(ga + 16) * 260 + c * 32 + dp];

    // MFMA: D[group 32][local row 192], K=512
    if (w < 6) {
      f32x16 acc;
#pragma unroll
      for (int i = 0; i < 16; ++i) acc[i] = 0.0f;
#pragma unroll
      for (int ks = 0; ks < 32; ++ks) {
        const half8 af = *(const half8*)&h_l[l31 * 260 + ks * 8 + kh * 4];
        acc = __builtin_amdgcn_mfma_f32_32x32x16_f16(af, bf[ks], acc, 0, 0, 0);
      }
      // C/D map (verified): col=lane&31 -> local row, row=(r&3)+8*(r>>2)+4*kh -> group
#pragma unroll
      for (int r = 0; r < 16; ++r) {
        const int grp = (r & 3) + 8 * (r >> 2) + 4 * kh;
        sg[(w * 32 + l31) * 33 + grp] = acc[r];
      }
    }
    __syncthreads();   // B2

    // epilogue: gates for 2 groups x 2 dims
#pragma unroll
    for (int gi = 0; gi < 2; ++gi) {
      const int g = ga + gi * 16;
      const half2t hp2 = __builtin_bit_cast(half2t, gi ? hpb : hpa);
      float hn[2];
#pragma unroll
      for (int dd = 0; dd < 2; ++dd) {
        const int d = 2 * dp + dd;
        const half2t xr2 = __builtin_bit_cast(half2t, xu[0][gi]);
        const half2t xz2 = __builtin_bit_cast(half2t, xu[1][gi]);
        const half2t xn2 = __builtin_bit_cast(half2t, xu[2][gi]);
        const float xr = (float)(dd ? xr2.y : xr2.x);
        const float xz = (float)(dd ? xz2.y : xz2.x);
        const float xn = (float)(dd ? xn2.y : xn2.x);
        const float hprev = (float)(dd ? hp2.y : hp2.x);
        const float rr = fast_sigmoid(xr + sg[(0 * 64 + d) * 33 + g] + bias[0][dd]);
        const float zz = fast_sigmoid(xz + sg[(64 + d) * 33 + g] + bias[1][dd]);
        const float nn = tanhf(xn + rr * (sg[(128 + d) * 33 + g] + bias[2][dd]));
        hn[dd] = (1.0f - zz) * nn + zz * hprev;
      }
      llc_store32(&hbuf[(size_t)((t + 1) & 1) * (BATCH * 256) + g * 256 + c * 32 + dp],
                  pack2h(hn[0], hn[1]));
      store_out2(&hout[((size_t)g * TLEN + t) * HDIM + c * 64 + 2 * dp], hn[0], hn[1]);
    }
    // drain THIS wave's stores, then publish this wave's flag
    asm volatile("s_waitcnt vmcnt(0)" ::: "memory");
    if (lane == 0)
      __hip_atomic_store(&flags[c * 8 + w], (u32)(t + 1),
                         __ATOMIC_RELAXED, __HIP_MEMORY_SCOPE_AGENT);
  }
}

// ---------------- host launcher ----------------
extern "C" void kernel_launch(void* const* d_in, const int* in_sizes, int n_in,
                              void* d_out, int out_size, void* d_ws, size_t ws_size,
                              hipStream_t stream)
{
  const float* x     = (const float*)d_in[0];
  const float* gamma = (const float*)d_in[1];
  const float* beta  = (const float*)d_in[2];
  const float* Wih   = (const float*)d_in[3];
  const float* Whh   = (const float*)d_in[4];
  const float* bih   = (const float*)d_in[5];
  const float* bhh   = (const float*)d_in[6];
  float* out = (float*)d_out;

  const size_t wbytes  = (size_t)2 * G3 * HDIM * 2;
  const size_t h1bytes = (size_t)BATCH * TLEN * HDIM * 2;
  const size_t fixed   = h1bytes + 2 * wbytes + (size_t)2 * BATCH * 256 * 4 + 64 * 4 + 4096;
  int lgT = 11;
  while (lgT > 2 && ((size_t)BATCH * ((size_t)1 << lgT) * G3 * 2 + fixed) > ws_size) --lgT;
  const int TSEG = 1 << lgT;
  const int nseg = TLEN / TSEG;

  char* ws = (char*)d_ws;
  _Float16* xp    = (_Float16*)ws;
  char* base      = ws + (size_t)BATCH * TSEG * G3 * 2;
  _Float16* h1    = (_Float16*)base;
  _Float16* wih_h = (_Float16*)(base + h1bytes);
  _Float16* whh_h = (_Float16*)(base + h1bytes + wbytes);
  u32*      hbuf  = (u32*)     (base + h1bytes + 2 * wbytes);
  u32*      flags = (u32*)     (base + h1bytes + 2 * wbytes + (size_t)2 * BATCH * 256 * 4);
  _Float16* hseq  = (_Float16*)d_out;   // LN output staging (fp16) — consumed before fp32 writes

  convert_weights<<<512, 256, 0, stream>>>(Wih, Whh, wih_h, whh_h);
  ln_kernel<<<BATCH * TLEN, 256, 0, stream>>>(x, gamma, beta, hseq);

  const dim3 ggrid(BATCH * TSEG / 128, 12);

  // layer 1
  init_sync<<<64, 256, 0, stream>>>(hbuf, flags);
  for (int s = 0; s < nseg; ++s) {
    const int t0 = s * TSEG;
    gemm_f16<<<ggrid, 256, 0, stream>>>(hseq, wih_h, bih, xp, t0, lgT);
    gru_rec<_Float16><<<8, 512, 0, stream>>>((const u32*)xp, (const u32*)whh_h, bhh,
                                             h1, hbuf, flags, t0, t0 + TSEG, lgT);
  }
  // layer 2
  init_sync<<<64, 256, 0, stream>>>(hbuf, flags);
  for (int s = 0; s < nseg; ++s) {
    const int t0 = s * TSEG;
    gemm_f16<<<ggrid, 256, 0, stream>>>(h1, wih_h + (size_t)G3 * HDIM, bih + G3, xp, t0, lgT);
    gru_rec<float><<<8, 512, 0, stream>>>((const u32*)xp, (const u32*)(whh_h + (size_t)G3 * HDIM),
                                          bhh + G3, out, hbuf, flags, t0, t0 + TSEG, lgT);
  }
}

// Round 6
// 22115.535 us; speedup vs baseline: 3.8437x; 1.5006x over previous
//
#include <hip/hip_runtime.h>
#include <hip/hip_fp16.h>

typedef float f32x4 __attribute__((ext_vector_type(4)));
typedef float f32x16 __attribute__((ext_vector_type(16)));
typedef _Float16 half8 __attribute__((ext_vector_type(8)));
typedef _Float16 half2t __attribute__((ext_vector_type(2)));
typedef unsigned int u32;

#define DEVI static __device__ __forceinline__

constexpr int BATCH = 32;
constexpr int TLEN  = 2048;
constexpr int HDIM  = 512;
constexpr int G3    = 1536;   // 3*H

DEVI float fast_sigmoid(float x) { return 1.0f / (1.0f + __expf(-x)); }

DEVI u32 pack2h(float a, float b) {
  return __builtin_bit_cast(u32, __builtin_amdgcn_cvt_pkrtz(a, b));
}

DEVI u32 llc_load32(const u32* p) {
  return __hip_atomic_load(p, __ATOMIC_RELAXED, __HIP_MEMORY_SCOPE_AGENT);
}
DEVI void llc_store32(u32* p, u32 v) {
  __hip_atomic_store(p, v, __ATOMIC_RELAXED, __HIP_MEMORY_SCOPE_AGENT);
}

// ---------------- weight conversion (fp32 -> fp16) ----------------
__global__ void convert_weights(const float* __restrict__ wih, const float* __restrict__ whh,
                                _Float16* __restrict__ wih_h, _Float16* __restrict__ whh_h)
{
  const size_t n = (size_t)2 * G3 * HDIM;
  for (size_t i = (size_t)blockIdx.x * blockDim.x + threadIdx.x; i < n;
       i += (size_t)gridDim.x * blockDim.x) {
    wih_h[i] = (_Float16)wih[i];
    whh_h[i] = (_Float16)whh[i];
  }
}

// ---------------- layernorm: fp32 in -> fp16 out ----------------
__global__ __launch_bounds__(256) void ln_kernel(const float* __restrict__ x,
    const float* __restrict__ gamma, const float* __restrict__ beta,
    _Float16* __restrict__ out)
{
  const int row = blockIdx.x;
  const int tid = threadIdx.x;
  const float* xr = x + (size_t)row * HDIM;
  float a = xr[tid], b = xr[tid + 256];
  float s = a + b, ss = a * a + b * b;
#pragma unroll
  for (int m = 1; m < 64; m <<= 1) {
    s  += __shfl_xor(s, m, 64);
    ss += __shfl_xor(ss, m, 64);
  }
  __shared__ float sb[8];
  const int w = tid >> 6;
  if ((tid & 63) == 0) { sb[w] = s; sb[4 + w] = ss; }
  __syncthreads();
  s  = sb[0] + sb[1] + sb[2] + sb[3];
  ss = sb[4] + sb[5] + sb[6] + sb[7];
  const float mu   = s * (1.0f / HDIM);
  const float var  = ss * (1.0f / HDIM) - mu * mu;
  const float rstd = rsqrtf(var + 1e-5f);
  out[(size_t)row * HDIM + tid]       = (_Float16)((a - mu) * rstd * gamma[tid] + beta[tid]);
  out[(size_t)row * HDIM + tid + 256] = (_Float16)((b - mu) * rstd * gamma[tid + 256] + beta[tid + 256]);
}

// ---------------- fp16 MFMA GEMM: C[m,n] = sum_k A[m,k]*W[n,k] + bias[n] ----------------
__global__ __launch_bounds__(256) void gemm_f16(
    const _Float16* __restrict__ A, const _Float16* __restrict__ W,
    const float* __restrict__ bias, _Float16* __restrict__ C,
    int t0, int lgT)
{
  __shared__ _Float16 As[128][40];
  __shared__ _Float16 Bs[128][40];
  const int bm = blockIdx.x;
  const int bn = blockIdx.y;
  const int tid = threadIdx.x;
  const int lane = tid & 63;
  const int wv = tid >> 6;
  const int wm = wv >> 1, wn = wv & 1;
  const int l15 = lane & 15, g4 = lane >> 4;
  const int tmask = (1 << lgT) - 1;

  f32x4 zero4 = {0.f, 0.f, 0.f, 0.f};
  f32x4 acc[4][4];
#pragma unroll
  for (int i = 0; i < 4; ++i) {
#pragma unroll
    for (int j = 0; j < 4; ++j) acc[i][j] = zero4;
  }

  const int srow = tid >> 2;
  const int scol = (tid & 3) * 8;
  size_t arow[2];
#pragma unroll
  for (int r2 = 0; r2 < 2; ++r2) {
    int m = bm * 128 + r2 * 64 + srow;
    int b = m >> lgT, tt = m & tmask;
    arow[r2] = ((size_t)b * TLEN + (size_t)(t0 + tt)) * HDIM;
  }
  const size_t brow0 = (size_t)(bn * 128 + srow) * HDIM;

  for (int kt = 0; kt < HDIM; kt += 32) {
#pragma unroll
    for (int r2 = 0; r2 < 2; ++r2) {
      *(uint4*)&As[r2 * 64 + srow][scol] = *(const uint4*)&A[arow[r2] + kt + scol];
      *(uint4*)&Bs[r2 * 64 + srow][scol] = *(const uint4*)&W[brow0 + (size_t)r2 * 64 * HDIM + kt + scol];
    }
    __syncthreads();
    half8 af[4], bf[4];
#pragma unroll
    for (int i = 0; i < 4; ++i) af[i] = *(const half8*)&As[wm * 64 + i * 16 + l15][g4 * 8];
#pragma unroll
    for (int j = 0; j < 4; ++j) bf[j] = *(const half8*)&Bs[wn * 64 + j * 16 + l15][g4 * 8];
#pragma unroll
    for (int i = 0; i < 4; ++i) {
#pragma unroll
      for (int j = 0; j < 4; ++j)
        acc[i][j] = __builtin_amdgcn_mfma_f32_16x16x32_f16(af[i], bf[j], acc[i][j], 0, 0, 0);
    }
    __syncthreads();
  }
#pragma unroll
  for (int j = 0; j < 4; ++j) {
    const int col = bn * 128 + wn * 64 + j * 16 + l15;
    const float bi = bias[col];
#pragma unroll
    for (int i = 0; i < 4; ++i) {
      const int mrow = bm * 128 + wm * 64 + i * 16 + g4 * 4;
#pragma unroll
      for (int r = 0; r < 4; ++r)
        C[(size_t)(mrow + r) * G3 + col] = (_Float16)(acc[i][j][r] + bi);
    }
  }
}

// ---------------- sync-state init ----------------
__global__ void init_sync(u32* __restrict__ hbufs, u32* __restrict__ flags)
{
  const int i = blockIdx.x * 256 + threadIdx.x;
  if (i < 6 * 8192) hbufs[i] = 0u;   // h1buf[4 slots] + h2buf[2 slots], fp16 pairs (0,0)
  if (i < 256) flags[i] = 0u;
}

// ---------------- fused 2-layer persistent GRU recurrence ----------------
// 32 blocks: layer = bid>>4 (0: L1, 1: L2), c = bid&15 owns dims [c*32, c*32+32).
// 512 thr. MFMA waves 0-2: W_hh row-tiles (gate r,z,n); waves 3-5 (L2 only): W_ih2 tiles.
// One half8 bf[32] per wave = 128 VGPR. h1 via 4-slot ring; h2 via 2-slot parity.
// flags[2][16][8]; L1@t waits {L1>=t, L2>=t-3}; L2@t waits {L1>=t+1, L2>=t}.
__global__ __launch_bounds__(512, 1) void gru_fused(
    const u32* __restrict__ xp,        // [BATCH][TSEG][768] u32 (fp16 pairs), layer-1 xp
    const u32* __restrict__ whh,       // [2][G3][256] u32 (fp16 pairs)
    const u32* __restrict__ wih2,      // [G3][256] u32, layer-2 W_ih
    const float* __restrict__ bhh,     // [2*G3]
    const float* __restrict__ bih2,    // [G3]
    float* __restrict__ out,           // [BATCH][TLEN][HDIM] fp32
    u32* __restrict__ h1buf,           // [4][8192]
    u32* __restrict__ h2buf,           // [2][8192]
    u32* __restrict__ flags,           // [256]
    int t0, int t1, int lgT)
{
  const int l2 = blockIdx.x >> 4;
  const int c  = blockIdx.x & 15;
  const int tid = threadIdx.x;
  const int lane = tid & 63;
  const int w = tid >> 6;
  const int l31 = lane & 31;
  const int kh = lane >> 5;

  __shared__ u32 st_l[32 * 260];    // own state (h1 for L1 / h2 for L2)
  __shared__ u32 h1_l[32 * 260];    // L2 only: h1 input
  __shared__ float sg_h[96 * 33];   // W_hh result
  __shared__ float sg_i[96 * 33];   // W_ih2 result (L2)

  // one MFMA tile per wave: waves 0-2 -> W_hh gate tiles; waves 3-5 (L2) -> W_ih2 tiles
  half8 bf[32];
  const bool mfma_w = (w < 3) || (l2 && w < 6);
  if (mfma_w) {
    const int gt = (w < 3) ? w : w - 3;
    const int grow = gt * 512 + c * 32 + l31;
    const u32* wsrc = (w < 3) ? (whh + (size_t)l2 * (G3 * 256)) : wih2;
#pragma unroll
    for (int ks = 0; ks < 32; ++ks)
      bf[ks] = *(const half8*)&wsrc[(size_t)grow * 256 + ks * 8 + kh * 4];
  }

  // epilogue mapping: thread -> group g = tid>>4, dim pair dp = tid&15 (global dims c*32+2dp, +1)
  const int dp = tid & 15;
  const int ga = tid >> 4;
  const float* bhh_l = bhh + l2 * G3;
  float biasH[3][2], biasI[3][2];
#pragma unroll
  for (int gt = 0; gt < 3; ++gt) {
    biasH[gt][0] = bhh_l[gt * 512 + c * 32 + 2 * dp];
    biasH[gt][1] = bhh_l[gt * 512 + c * 32 + 2 * dp + 1];
    biasI[gt][0] = l2 ? bih2[gt * 512 + c * 32 + 2 * dp] : 0.0f;
    biasI[gt][1] = l2 ? bih2[gt * 512 + c * 32 + 2 * dp + 1] : 0.0f;
  }

  for (int t = t0; t < t1; ++t) {
    // L1: prefetch xp for this step (latency hides under poll)
    u32 xu[3];
    if (!l2) {
      const size_t row = ((size_t)(ga << lgT) + (size_t)(t - t0)) * 768;
#pragma unroll
      for (int gt = 0; gt < 3; ++gt)
        xu[gt] = xp[row + gt * 256 + c * 16 + dp];
    }
    // poll: lane covers flags[lane], [64+lane] (L1), [128+lane], [192+lane] (L2)
    {
      while (true) {
        int fa = (int)__hip_atomic_load(&flags[lane],       __ATOMIC_RELAXED, __HIP_MEMORY_SCOPE_AGENT);
        int fb = (int)__hip_atomic_load(&flags[64 + lane],  __ATOMIC_RELAXED, __HIP_MEMORY_SCOPE_AGENT);
        int fc = (int)__hip_atomic_load(&flags[128 + lane], __ATOMIC_RELAXED, __HIP_MEMORY_SCOPE_AGENT);
        int fd = (int)__hip_atomic_load(&flags[192 + lane], __ATOMIC_RELAXED, __HIP_MEMORY_SCOPE_AGENT);
        bool ok;
        if (!l2) ok = (fa >= t) && (fb >= t) && (fc >= t - 3) && (fd >= t - 3);
        else     ok = (fa >= t + 1) && (fb >= t + 1) && (fc >= t) && (fd >= t);
        if (__all((int)ok)) break;
        __builtin_amdgcn_s_sleep(1);
      }
    }
    // load own state (32KB) -> LDS
    const u32* stsrc = l2 ? (h2buf + (size_t)(t & 1) * 8192)
                          : (h1buf + (size_t)(t & 3) * 8192);
#pragma unroll
    for (int j = 0; j < 16; ++j) {
      const int i = j * 512 + tid;
      st_l[(i >> 8) * 260 + (i & 255)] = llc_load32(&stsrc[i]);
    }
    if (l2) {
      // h1 version t+1 (L1's output at step t) lives in slot (t+1)&3
      const u32* h1src = h1buf + (size_t)((t + 1) & 3) * 8192;
#pragma unroll
      for (int j = 0; j < 16; ++j) {
        const int i = j * 512 + tid;
        h1_l[(i >> 8) * 260 + (i & 255)] = llc_load32(&h1src[i]);
      }
    }
    __syncthreads();   // B1

    const u32 hpp = st_l[ga * 260 + c * 16 + dp];

    if (mfma_w) {
      f32x16 acc;
#pragma unroll
      for (int i = 0; i < 16; ++i) acc[i] = 0.0f;
      const u32* asrc = (w < 3) ? st_l : h1_l;
#pragma unroll
      for (int ks = 0; ks < 32; ++ks) {
        const half8 af = *(const half8*)&asrc[l31 * 260 + ks * 8 + kh * 4];
        acc = __builtin_amdgcn_mfma_f32_32x32x16_f16(af, bf[ks], acc, 0, 0, 0);
      }
      // C/D map (verified): col=l31 -> local row, row=(r&3)+8*(r>>2)+4*kh -> group
      const int gt = (w < 3) ? w : w - 3;
      float* sg = (w < 3) ? sg_h : sg_i;
#pragma unroll
      for (int r = 0; r < 16; ++r) {
        const int grp = (r & 3) + 8 * (r >> 2) + 4 * kh;
        sg[(gt * 32 + l31) * 33 + grp] = acc[r];
      }
    }
    __syncthreads();   // B2

    // epilogue: one group x one dim-pair per thread
    {
      const half2t hp2 = __builtin_bit_cast(half2t, hpp);
      float hn[2];
#pragma unroll
      for (int dd = 0; dd < 2; ++dd) {
        const int d = 2 * dp + dd;
        float xr, xz, xn;
        if (!l2) {
          const half2t xr2 = __builtin_bit_cast(half2t, xu[0]);
          const half2t xz2 = __builtin_bit_cast(half2t, xu[1]);
          const half2t xn2 = __builtin_bit_cast(half2t, xu[2]);
          xr = (float)(dd ? xr2.y : xr2.x);
          xz = (float)(dd ? xz2.y : xz2.x);
          xn = (float)(dd ? xn2.y : xn2.x);
        } else {
          xr = sg_i[(0 * 32 + d) * 33 + ga] + biasI[0][dd];
          xz = sg_i[(32 + d) * 33 + ga]     + biasI[1][dd];
          xn = sg_i[(64 + d) * 33 + ga]     + biasI[2][dd];
        }
        const float hprev = (float)(dd ? hp2.y : hp2.x);
        const float rr = fast_sigmoid(xr + sg_h[(0 * 32 + d) * 33 + ga] + biasH[0][dd]);
        const float zz = fast_sigmoid(xz + sg_h[(32 + d) * 33 + ga]     + biasH[1][dd]);
        const float nn = tanhf(xn + rr * (sg_h[(64 + d) * 33 + ga]      + biasH[2][dd]));
        hn[dd] = (1.0f - zz) * nn + zz * hprev;
      }
      if (!l2) {
        llc_store32(&h1buf[(size_t)((t + 1) & 3) * 8192 + ga * 256 + c * 16 + dp],
                    pack2h(hn[0], hn[1]));
      } else {
        llc_store32(&h2buf[(size_t)((t + 1) & 1) * 8192 + ga * 256 + c * 16 + dp],
                    pack2h(hn[0], hn[1]));
        float2 v; v.x = hn[0]; v.y = hn[1];
        *(float2*)&out[((size_t)ga * TLEN + t) * HDIM + c * 32 + 2 * dp] = v;
      }
    }
    // drain THIS wave's stores, then publish this wave's flag
    asm volatile("s_waitcnt vmcnt(0)" ::: "memory");
    if (lane == 0)
      __hip_atomic_store(&flags[l2 * 128 + c * 8 + w], (u32)(t + 1),
                         __ATOMIC_RELAXED, __HIP_MEMORY_SCOPE_AGENT);
  }
}

// ---------------- host launcher ----------------
extern "C" void kernel_launch(void* const* d_in, const int* in_sizes, int n_in,
                              void* d_out, int out_size, void* d_ws, size_t ws_size,
                              hipStream_t stream)
{
  const float* x     = (const float*)d_in[0];
  const float* gamma = (const float*)d_in[1];
  const float* beta  = (const float*)d_in[2];
  const float* Wih   = (const float*)d_in[3];
  const float* Whh   = (const float*)d_in[4];
  const float* bih   = (const float*)d_in[5];
  const float* bhh   = (const float*)d_in[6];
  float* out = (float*)d_out;

  // ws layout: [xp: 32*TSEG*1536*2][hseq: 67MB][wih_h][whh_h][h1buf 4][h2buf 2][flags]
  const size_t wbytes  = (size_t)2 * G3 * HDIM * 2;                 // 3,145,728 each
  const size_t hseqb   = (size_t)BATCH * TLEN * HDIM * 2;           // 67,108,864
  const size_t fixed   = hseqb + 2 * wbytes + (size_t)6 * 8192 * 4 + 256 * 4 + 4096;
  int lgT = 11;
  while (lgT > 2 && ((size_t)BATCH * ((size_t)1 << lgT) * G3 * 2 + fixed) > ws_size) --lgT;
  const int TSEG = 1 << lgT;
  const int nseg = TLEN / TSEG;

  char* ws = (char*)d_ws;
  _Float16* xp    = (_Float16*)ws;
  char* base      = ws + (size_t)BATCH * TSEG * G3 * 2;
  _Float16* hseq  = (_Float16*)base;                                // LN output (fp16)
  _Float16* wih_h = (_Float16*)(base + hseqb);
  _Float16* whh_h = (_Float16*)(base + hseqb + wbytes);
  u32*      h1buf = (u32*)     (base + hseqb + 2 * wbytes);
  u32*      h2buf = h1buf + (size_t)4 * 8192;
  u32*      flags = h2buf + (size_t)2 * 8192;

  convert_weights<<<512, 256, 0, stream>>>(Wih, Whh, wih_h, whh_h);
  ln_kernel<<<BATCH * TLEN, 256, 0, stream>>>(x, gamma, beta, hseq);
  init_sync<<<192, 256, 0, stream>>>(h1buf, flags);

  const dim3 ggrid(BATCH * TSEG / 128, 12);
  for (int s = 0; s < nseg; ++s) {
    const int t0 = s * TSEG;
    gemm_f16<<<ggrid, 256, 0, stream>>>(hseq, wih_h, bih, xp, t0, lgT);
    gru_fused<<<32, 512, 0, stream>>>((const u32*)xp, (const u32*)whh_h,
                                      (const u32*)(wih_h + (size_t)G3 * HDIM),
                                      bhh, bih + G3, out,
                                      h1buf, h2buf, flags, t0, t0 + TSEG, lgT);
  }
}

// Round 7
// 18893.059 us; speedup vs baseline: 4.4993x; 1.1706x over previous
//
#include <hip/hip_runtime.h>
#include <hip/hip_fp16.h>

typedef float f32x4 __attribute__((ext_vector_type(4)));
typedef float f32x16 __attribute__((ext_vector_type(16)));
typedef _Float16 half8 __attribute__((ext_vector_type(8)));
typedef _Float16 half2t __attribute__((ext_vector_type(2)));
typedef unsigned int u32;

#define DEVI static __device__ __forceinline__

constexpr int BATCH = 32;
constexpr int TLEN  = 2048;
constexpr int HDIM  = 512;
constexpr int G3    = 1536;   // 3*H

DEVI float fast_sigmoid(float x) { return 1.0f / (1.0f + __expf(-x)); }

DEVI float fast_tanh(float x) {
  const float ax = fabsf(x);
  const float t = __expf(-2.0f * ax);
  const float r = (1.0f - t) / (1.0f + t);
  return copysignf(r, x);
}

DEVI u32 pack2h(float a, float b) {
  return __builtin_bit_cast(u32, __builtin_amdgcn_cvt_pkrtz(a, b));
}

DEVI u32 llc_load32(const u32* p) {
  return __hip_atomic_load(p, __ATOMIC_RELAXED, __HIP_MEMORY_SCOPE_AGENT);
}
DEVI void llc_store32(u32* p, u32 v) {
  __hip_atomic_store(p, v, __ATOMIC_RELAXED, __HIP_MEMORY_SCOPE_AGENT);
}

// ---------------- weight conversion (fp32 -> fp16) ----------------
__global__ void convert_weights(const float* __restrict__ wih, const float* __restrict__ whh,
                                _Float16* __restrict__ wih_h, _Float16* __restrict__ whh_h)
{
  const size_t n = (size_t)2 * G3 * HDIM;
  for (size_t i = (size_t)blockIdx.x * blockDim.x + threadIdx.x; i < n;
       i += (size_t)gridDim.x * blockDim.x) {
    wih_h[i] = (_Float16)wih[i];
    whh_h[i] = (_Float16)whh[i];
  }
}

// ---------------- layernorm: fp32 in -> fp16 out ----------------
__global__ __launch_bounds__(256) void ln_kernel(const float* __restrict__ x,
    const float* __restrict__ gamma, const float* __restrict__ beta,
    _Float16* __restrict__ out)
{
  const int row = blockIdx.x;
  const int tid = threadIdx.x;
  const float* xr = x + (size_t)row * HDIM;
  float a = xr[tid], b = xr[tid + 256];
  float s = a + b, ss = a * a + b * b;
#pragma unroll
  for (int m = 1; m < 64; m <<= 1) {
    s  += __shfl_xor(s, m, 64);
    ss += __shfl_xor(ss, m, 64);
  }
  __shared__ float sb[8];
  const int w = tid >> 6;
  if ((tid & 63) == 0) { sb[w] = s; sb[4 + w] = ss; }
  __syncthreads();
  s  = sb[0] + sb[1] + sb[2] + sb[3];
  ss = sb[4] + sb[5] + sb[6] + sb[7];
  const float mu   = s * (1.0f / HDIM);
  const float var  = ss * (1.0f / HDIM) - mu * mu;
  const float rstd = rsqrtf(var + 1e-5f);
  out[(size_t)row * HDIM + tid]       = (_Float16)((a - mu) * rstd * gamma[tid] + beta[tid]);
  out[(size_t)row * HDIM + tid + 256] = (_Float16)((b - mu) * rstd * gamma[tid + 256] + beta[tid + 256]);
}

// ---------------- fp16 MFMA GEMM: C[m,n] = sum_k A[m,k]*W[n,k] + bias[n] ----------------
__global__ __launch_bounds__(256) void gemm_f16(
    const _Float16* __restrict__ A, const _Float16* __restrict__ W,
    const float* __restrict__ bias, _Float16* __restrict__ C,
    int t0, int lgT)
{
  __shared__ _Float16 As[128][40];
  __shared__ _Float16 Bs[128][40];
  const int bm = blockIdx.x;
  const int bn = blockIdx.y;
  const int tid = threadIdx.x;
  const int lane = tid & 63;
  const int wv = tid >> 6;
  const int wm = wv >> 1, wn = wv & 1;
  const int l15 = lane & 15, g4 = lane >> 4;
  const int tmask = (1 << lgT) - 1;

  f32x4 zero4 = {0.f, 0.f, 0.f, 0.f};
  f32x4 acc[4][4];
#pragma unroll
  for (int i = 0; i < 4; ++i) {
#pragma unroll
    for (int j = 0; j < 4; ++j) acc[i][j] = zero4;
  }

  const int srow = tid >> 2;
  const int scol = (tid & 3) * 8;
  size_t arow[2];
#pragma unroll
  for (int r2 = 0; r2 < 2; ++r2) {
    int m = bm * 128 + r2 * 64 + srow;
    int b = m >> lgT, tt = m & tmask;
    arow[r2] = ((size_t)b * TLEN + (size_t)(t0 + tt)) * HDIM;
  }
  const size_t brow0 = (size_t)(bn * 128 + srow) * HDIM;

  for (int kt = 0; kt < HDIM; kt += 32) {
#pragma unroll
    for (int r2 = 0; r2 < 2; ++r2) {
      *(uint4*)&As[r2 * 64 + srow][scol] = *(const uint4*)&A[arow[r2] + kt + scol];
      *(uint4*)&Bs[r2 * 64 + srow][scol] = *(const uint4*)&W[brow0 + (size_t)r2 * 64 * HDIM + kt + scol];
    }
    __syncthreads();
    half8 af[4], bf[4];
#pragma unroll
    for (int i = 0; i < 4; ++i) af[i] = *(const half8*)&As[wm * 64 + i * 16 + l15][g4 * 8];
#pragma unroll
    for (int j = 0; j < 4; ++j) bf[j] = *(const half8*)&Bs[wn * 64 + j * 16 + l15][g4 * 8];
#pragma unroll
    for (int i = 0; i < 4; ++i) {
#pragma unroll
      for (int j = 0; j < 4; ++j)
        acc[i][j] = __builtin_amdgcn_mfma_f32_16x16x32_f16(af[i], bf[j], acc[i][j], 0, 0, 0);
    }
    __syncthreads();
  }
#pragma unroll
  for (int j = 0; j < 4; ++j) {
    const int col = bn * 128 + wn * 64 + j * 16 + l15;
    const float bi = bias[col];
#pragma unroll
    for (int i = 0; i < 4; ++i) {
      const int mrow = bm * 128 + wm * 64 + i * 16 + g4 * 4;
#pragma unroll
      for (int r = 0; r < 4; ++r)
        C[(size_t)(mrow + r) * G3 + col] = (_Float16)(acc[i][j][r] + bi);
    }
  }
}

// ---------------- sync-state init ----------------
__global__ void init_sync(u32* __restrict__ hbufs, u32* __restrict__ flags)
{
  const int i = blockIdx.x * 256 + threadIdx.x;
  if (i < 6 * 8192) hbufs[i] = 0u;   // h1buf[4 slots] + h2buf[2 slots], fp16 pairs (0,0)
  if (i < 64) flags[i] = 0u;         // cnt0 at [0], cnt1 at [16]
}

// ---------------- fused 2-layer persistent GRU recurrence ----------------
// 32 blocks: layer = bid>>4 (0: L1, 1: L2), c = bid&15 owns dims [c*32, c*32+32).
// Sync: two global step-counters (64B apart). Block publishes ONE atomicAdd per step
// after per-wave vmcnt drain + barrier; only wave 0 polls, then barrier releases block.
// L1@t waits {cntL1>=16t, cntL2>=16(t-3)}; L2@t waits {cntL1>=16(t+1), cntL2>=16t}.
__global__ __launch_bounds__(512, 1) void gru_fused(
    const u32* __restrict__ xp,        // [BATCH][TSEG][768] u32 (fp16 pairs), layer-1 xp
    const u32* __restrict__ whh,       // [2][G3][256] u32 (fp16 pairs)
    const u32* __restrict__ wih2,      // [G3][256] u32, layer-2 W_ih
    const float* __restrict__ bhh,     // [2*G3]
    const float* __restrict__ bih2,    // [G3]
    float* __restrict__ out,           // [BATCH][TLEN][HDIM] fp32
    u32* __restrict__ h1buf,           // [4][8192]
    u32* __restrict__ h2buf,           // [2][8192]
    u32* __restrict__ flags,           // [64]: cnt0=[0], cnt1=[16]
    int t0, int t1, int lgT)
{
  const int l2 = blockIdx.x >> 4;
  const int c  = blockIdx.x & 15;
  const int tid = threadIdx.x;
  const int lane = tid & 63;
  const int w = tid >> 6;
  const int l31 = lane & 31;
  const int kh = lane >> 5;

  __shared__ u32 st_l[32 * 260];    // own state (h1 for L1 / h2 for L2)
  __shared__ u32 h1_l[32 * 260];    // L2 only: h1 input
  __shared__ float sg_h[96 * 33];   // W_hh result
  __shared__ float sg_i[96 * 33];   // W_ih2 result (L2)

  // one MFMA tile per wave: waves 0-2 -> W_hh gate tiles; waves 3-5 (L2) -> W_ih2 tiles
  half8 bf[32];
  const bool mfma_w = (w < 3) || (l2 && w < 6);
  if (mfma_w) {
    const int gt = (w < 3) ? w : w - 3;
    const int grow = gt * 512 + c * 32 + l31;
    const u32* wsrc = (w < 3) ? (whh + (size_t)l2 * (G3 * 256)) : wih2;
#pragma unroll
    for (int ks = 0; ks < 32; ++ks)
      bf[ks] = *(const half8*)&wsrc[(size_t)grow * 256 + ks * 8 + kh * 4];
  }

  // epilogue mapping: thread -> group g = tid>>4, dim pair dp = tid&15 (global dims c*32+2dp, +1)
  const int dp = tid & 15;
  const int ga = tid >> 4;
  const float* bhh_l = bhh + l2 * G3;
  float biasH[3][2], biasI[3][2];
#pragma unroll
  for (int gt = 0; gt < 3; ++gt) {
    biasH[gt][0] = bhh_l[gt * 512 + c * 32 + 2 * dp];
    biasH[gt][1] = bhh_l[gt * 512 + c * 32 + 2 * dp + 1];
    biasI[gt][0] = l2 ? bih2[gt * 512 + c * 32 + 2 * dp] : 0.0f;
    biasI[gt][1] = l2 ? bih2[gt * 512 + c * 32 + 2 * dp + 1] : 0.0f;
  }

  for (int t = t0; t < t1; ++t) {
    // L1: prefetch xp for this step (overlaps peers' poll/barrier)
    u32 xu[3];
    if (!l2) {
      const size_t row = ((size_t)(ga << lgT) + (size_t)(t - t0)) * 768;
#pragma unroll
      for (int gt = 0; gt < 3; ++gt)
        xu[gt] = xp[row + gt * 256 + c * 16 + dp];
    }
    // wave 0 polls the two step-counters; rest of block waits at B0
    if (w == 0) {
      const int n1 = l2 ? 16 * (t + 1) : 16 * t;
      const int n2 = l2 ? 16 * t       : 16 * (t - 3);
      while (true) {
        const int c1 = (int)llc_load32(&flags[0]);
        const int c2 = (int)llc_load32(&flags[16]);
        if (c1 >= n1 && c2 >= n2) break;
        __builtin_amdgcn_s_sleep(1);
      }
    }
    __syncthreads();   // B0: quorum reached

    // load own state (32KB) -> LDS
    const u32* stsrc = l2 ? (h2buf + (size_t)(t & 1) * 8192)
                          : (h1buf + (size_t)(t & 3) * 8192);
#pragma unroll
    for (int j = 0; j < 16; ++j) {
      const int i = j * 512 + tid;
      st_l[(i >> 8) * 260 + (i & 255)] = llc_load32(&stsrc[i]);
    }
    if (l2) {
      // h1 version t+1 (L1's output at step t) lives in slot (t+1)&3
      const u32* h1src = h1buf + (size_t)((t + 1) & 3) * 8192;
#pragma unroll
      for (int j = 0; j < 16; ++j) {
        const int i = j * 512 + tid;
        h1_l[(i >> 8) * 260 + (i & 255)] = llc_load32(&h1src[i]);
      }
    }
    __syncthreads();   // B1

    const u32 hpp = st_l[ga * 260 + c * 16 + dp];

    if (mfma_w) {
      f32x16 acc;
#pragma unroll
      for (int i = 0; i < 16; ++i) acc[i] = 0.0f;
      const u32* asrc = (w < 3) ? st_l : h1_l;
#pragma unroll
      for (int ks = 0; ks < 32; ++ks) {
        const half8 af = *(const half8*)&asrc[l31 * 260 + ks * 8 + kh * 4];
        acc = __builtin_amdgcn_mfma_f32_32x32x16_f16(af, bf[ks], acc, 0, 0, 0);
      }
      // C/D map (verified): col=l31 -> local row, row=(r&3)+8*(r>>2)+4*kh -> group
      const int gt = (w < 3) ? w : w - 3;
      float* sg = (w < 3) ? sg_h : sg_i;
#pragma unroll
      for (int r = 0; r < 16; ++r) {
        const int grp = (r & 3) + 8 * (r >> 2) + 4 * kh;
        sg[(gt * 32 + l31) * 33 + grp] = acc[r];
      }
    }
    __syncthreads();   // B2

    // epilogue: one group x one dim-pair per thread
    float hn0, hn1;
    {
      const half2t hp2 = __builtin_bit_cast(half2t, hpp);
      float hn[2];
#pragma unroll
      for (int dd = 0; dd < 2; ++dd) {
        const int d = 2 * dp + dd;
        float xr, xz, xn;
        if (!l2) {
          const half2t xr2 = __builtin_bit_cast(half2t, xu[0]);
          const half2t xz2 = __builtin_bit_cast(half2t, xu[1]);
          const half2t xn2 = __builtin_bit_cast(half2t, xu[2]);
          xr = (float)(dd ? xr2.y : xr2.x);
          xz = (float)(dd ? xz2.y : xz2.x);
          xn = (float)(dd ? xn2.y : xn2.x);
        } else {
          xr = sg_i[(0 * 32 + d) * 33 + ga] + biasI[0][dd];
          xz = sg_i[(32 + d) * 33 + ga]     + biasI[1][dd];
          xn = sg_i[(64 + d) * 33 + ga]     + biasI[2][dd];
        }
        const float hprev = (float)(dd ? hp2.y : hp2.x);
        const float rr = fast_sigmoid(xr + sg_h[(0 * 32 + d) * 33 + ga] + biasH[0][dd]);
        const float zz = fast_sigmoid(xz + sg_h[(32 + d) * 33 + ga]     + biasH[1][dd]);
        const float nn = fast_tanh(xn + rr * (sg_h[(64 + d) * 33 + ga]  + biasH[2][dd]));
        hn[dd] = (1.0f - zz) * nn + zz * hprev;
      }
      hn0 = hn[0]; hn1 = hn[1];
      // h-state store only (fp32 out store deferred past the publish)
      if (!l2) {
        llc_store32(&h1buf[(size_t)((t + 1) & 3) * 8192 + ga * 256 + c * 16 + dp],
                    pack2h(hn0, hn1));
      } else {
        llc_store32(&h2buf[(size_t)((t + 1) & 1) * 8192 + ga * 256 + c * 16 + dp],
                    pack2h(hn0, hn1));
      }
    }
    // per-wave drain, block-wide rendezvous, ONE publish per block
    asm volatile("s_waitcnt vmcnt(0)" ::: "memory");
    __syncthreads();   // B3: all waves' h stores are at the coherence point
    if (tid == 0)
      __hip_atomic_fetch_add(&flags[l2 * 16], 1u,
                             __ATOMIC_RELAXED, __HIP_MEMORY_SCOPE_AGENT);
    // deferred output store (not on the critical sync path)
    if (l2) {
      float2 v; v.x = hn0; v.y = hn1;
      *(float2*)&out[((size_t)ga * TLEN + t) * HDIM + c * 32 + 2 * dp] = v;
    }
  }
}

// ---------------- host launcher ----------------
extern "C" void kernel_launch(void* const* d_in, const int* in_sizes, int n_in,
                              void* d_out, int out_size, void* d_ws, size_t ws_size,
                              hipStream_t stream)
{
  const float* x     = (const float*)d_in[0];
  const float* gamma = (const float*)d_in[1];
  const float* beta  = (const float*)d_in[2];
  const float* Wih   = (const float*)d_in[3];
  const float* Whh   = (const float*)d_in[4];
  const float* bih   = (const float*)d_in[5];
  const float* bhh   = (const float*)d_in[6];
  float* out = (float*)d_out;

  // ws layout: [xp: 32*TSEG*1536*2][hseq: 67MB][wih_h][whh_h][h1buf 4][h2buf 2][flags]
  const size_t wbytes  = (size_t)2 * G3 * HDIM * 2;                 // 3,145,728 each
  const size_t hseqb   = (size_t)BATCH * TLEN * HDIM * 2;           // 67,108,864
  const size_t fixed   = hseqb + 2 * wbytes + (size_t)6 * 8192 * 4 + 64 * 4 + 4096;
  int lgT = 11;
  while (lgT > 2 && ((size_t)BATCH * ((size_t)1 << lgT) * G3 * 2 + fixed) > ws_size) --lgT;
  const int TSEG = 1 << lgT;
  const int nseg = TLEN / TSEG;

  char* ws = (char*)d_ws;
  _Float16* xp    = (_Float16*)ws;
  char* base      = ws + (size_t)BATCH * TSEG * G3 * 2;
  _Float16* hseq  = (_Float16*)base;                                // LN output (fp16)
  _Float16* wih_h = (_Float16*)(base + hseqb);
  _Float16* whh_h = (_Float16*)(base + hseqb + wbytes);
  u32*      h1buf = (u32*)     (base + hseqb + 2 * wbytes);
  u32*      h2buf = h1buf + (size_t)4 * 8192;
  u32*      flags = h2buf + (size_t)2 * 8192;

  convert_weights<<<512, 256, 0, stream>>>(Wih, Whh, wih_h, whh_h);
  ln_kernel<<<BATCH * TLEN, 256, 0, stream>>>(x, gamma, beta, hseq);
  init_sync<<<192, 256, 0, stream>>>(h1buf, flags);

  const dim3 ggrid(BATCH * TSEG / 128, 12);
  for (int s = 0; s < nseg; ++s) {
    const int t0 = s * TSEG;
    gemm_f16<<<ggrid, 256, 0, stream>>>(hseq, wih_h, bih, xp, t0, lgT);
    gru_fused<<<32, 512, 0, stream>>>((const u32*)xp, (const u32*)whh_h,
                                      (const u32*)(wih_h + (size_t)G3 * HDIM),
                                      bhh, bih + G3, out,
                                      h1buf, h2buf, flags, t0, t0 + TSEG, lgT);
  }
}

// Round 8
// 18684.753 us; speedup vs baseline: 4.5494x; 1.0111x over previous
//
#include <hip/hip_runtime.h>
#include <hip/hip_fp16.h>

typedef float f32x4 __attribute__((ext_vector_type(4)));
typedef float f32x16 __attribute__((ext_vector_type(16)));
typedef _Float16 half8 __attribute__((ext_vector_type(8)));
typedef _Float16 half2t __attribute__((ext_vector_type(2)));
typedef unsigned int u32;

#define DEVI static __device__ __forceinline__

constexpr int BATCH = 32;
constexpr int TLEN  = 2048;
constexpr int HDIM  = 512;
constexpr int G3    = 1536;   // 3*H

DEVI float fast_sigmoid(float x) { return 1.0f / (1.0f + __expf(-x)); }

DEVI float fast_tanh(float x) {
  const float ax = fabsf(x);
  const float t = __expf(-2.0f * ax);
  const float r = (1.0f - t) / (1.0f + t);
  return copysignf(r, x);
}

DEVI u32 pack2h(float a, float b) {
  return __builtin_bit_cast(u32, __builtin_amdgcn_cvt_pkrtz(a, b));
}

DEVI u32 llc_load32(const u32* p) {
  return __hip_atomic_load(p, __ATOMIC_RELAXED, __HIP_MEMORY_SCOPE_AGENT);
}
DEVI void llc_store32(u32* p, u32 v) {
  __hip_atomic_store(p, v, __ATOMIC_RELAXED, __HIP_MEMORY_SCOPE_AGENT);
}

// ---------------- weight conversion (fp32 -> fp16) ----------------
__global__ void convert_weights(const float* __restrict__ wih, const float* __restrict__ whh,
                                _Float16* __restrict__ wih_h, _Float16* __restrict__ whh_h)
{
  const size_t n = (size_t)2 * G3 * HDIM;
  for (size_t i = (size_t)blockIdx.x * blockDim.x + threadIdx.x; i < n;
       i += (size_t)gridDim.x * blockDim.x) {
    wih_h[i] = (_Float16)wih[i];
    whh_h[i] = (_Float16)whh[i];
  }
}

// ---------------- layernorm: fp32 in -> fp16 out ----------------
__global__ __launch_bounds__(256) void ln_kernel(const float* __restrict__ x,
    const float* __restrict__ gamma, const float* __restrict__ beta,
    _Float16* __restrict__ out)
{
  const int row = blockIdx.x;
  const int tid = threadIdx.x;
  const float* xr = x + (size_t)row * HDIM;
  float a = xr[tid], b = xr[tid + 256];
  float s = a + b, ss = a * a + b * b;
#pragma unroll
  for (int m = 1; m < 64; m <<= 1) {
    s  += __shfl_xor(s, m, 64);
    ss += __shfl_xor(ss, m, 64);
  }
  __shared__ float sb[8];
  const int w = tid >> 6;
  if ((tid & 63) == 0) { sb[w] = s; sb[4 + w] = ss; }
  __syncthreads();
  s  = sb[0] + sb[1] + sb[2] + sb[3];
  ss = sb[4] + sb[5] + sb[6] + sb[7];
  const float mu   = s * (1.0f / HDIM);
  const float var  = ss * (1.0f / HDIM) - mu * mu;
  const float rstd = rsqrtf(var + 1e-5f);
  out[(size_t)row * HDIM + tid]       = (_Float16)((a - mu) * rstd * gamma[tid] + beta[tid]);
  out[(size_t)row * HDIM + tid + 256] = (_Float16)((b - mu) * rstd * gamma[tid + 256] + beta[tid + 256]);
}

// ---------------- fp16 MFMA GEMM: C[m,n] = sum_k A[m,k]*W[n,k] + bias[n] ----------------
__global__ __launch_bounds__(256) void gemm_f16(
    const _Float16* __restrict__ A, const _Float16* __restrict__ W,
    const float* __restrict__ bias, _Float16* __restrict__ C,
    int t0, int lgT)
{
  __shared__ _Float16 As[128][40];
  __shared__ _Float16 Bs[128][40];
  const int bm = blockIdx.x;
  const int bn = blockIdx.y;
  const int tid = threadIdx.x;
  const int lane = tid & 63;
  const int wv = tid >> 6;
  const int wm = wv >> 1, wn = wv & 1;
  const int l15 = lane & 15, g4 = lane >> 4;
  const int tmask = (1 << lgT) - 1;

  f32x4 zero4 = {0.f, 0.f, 0.f, 0.f};
  f32x4 acc[4][4];
#pragma unroll
  for (int i = 0; i < 4; ++i) {
#pragma unroll
    for (int j = 0; j < 4; ++j) acc[i][j] = zero4;
  }

  const int srow = tid >> 2;
  const int scol = (tid & 3) * 8;
  size_t arow[2];
#pragma unroll
  for (int r2 = 0; r2 < 2; ++r2) {
    int m = bm * 128 + r2 * 64 + srow;
    int b = m >> lgT, tt = m & tmask;
    arow[r2] = ((size_t)b * TLEN + (size_t)(t0 + tt)) * HDIM;
  }
  const size_t brow0 = (size_t)(bn * 128 + srow) * HDIM;

  for (int kt = 0; kt < HDIM; kt += 32) {
#pragma unroll
    for (int r2 = 0; r2 < 2; ++r2) {
      *(uint4*)&As[r2 * 64 + srow][scol] = *(const uint4*)&A[arow[r2] + kt + scol];
      *(uint4*)&Bs[r2 * 64 + srow][scol] = *(const uint4*)&W[brow0 + (size_t)r2 * 64 * HDIM + kt + scol];
    }
    __syncthreads();
    half8 af[4], bf[4];
#pragma unroll
    for (int i = 0; i < 4; ++i) af[i] = *(const half8*)&As[wm * 64 + i * 16 + l15][g4 * 8];
#pragma unroll
    for (int j = 0; j < 4; ++j) bf[j] = *(const half8*)&Bs[wn * 64 + j * 16 + l15][g4 * 8];
#pragma unroll
    for (int i = 0; i < 4; ++i) {
#pragma unroll
      for (int j = 0; j < 4; ++j)
        acc[i][j] = __builtin_amdgcn_mfma_f32_16x16x32_f16(af[i], bf[j], acc[i][j], 0, 0, 0);
    }
    __syncthreads();
  }
#pragma unroll
  for (int j = 0; j < 4; ++j) {
    const int col = bn * 128 + wn * 64 + j * 16 + l15;
    const float bi = bias[col];
#pragma unroll
    for (int i = 0; i < 4; ++i) {
      const int mrow = bm * 128 + wm * 64 + i * 16 + g4 * 4;
#pragma unroll
      for (int r = 0; r < 4; ++r)
        C[(size_t)(mrow + r) * G3 + col] = (_Float16)(acc[i][j][r] + bi);
    }
  }
}

// ---------------- sync-state init ----------------
__global__ void init_sync(u32* __restrict__ hbufs, u32* __restrict__ flags)
{
  const int i = blockIdx.x * 256 + threadIdx.x;
  if (i < 6 * 8192) hbufs[i] = 0u;   // h1buf[4 slots] + h2buf[2 slots], fp16 pairs (0,0)
  if (i < 64) flags[i] = 0u;         // L1 flags [0..15], L2 flags [32..47]
}

// ---------------- fused 2-layer persistent GRU recurrence ----------------
// 32 blocks: layer = bid>>4 (0: L1, 1: L2), c = bid&15 owns dims [c*32, c*32+32).
// Sync: 16 per-block flag words per layer (one cacheline each; PARALLEL plain stores,
// no RMW). Wave 0 polls both lines; barrier releases the block. Publish: per-wave
// vmcnt drain + barrier, then tid0 stores flag = t+1.
// L1@t waits {L1 flags >= t, L2 flags >= t-3}; L2@t waits {L1 >= t+1, L2 >= t}.
__global__ __launch_bounds__(512, 1) void gru_fused(
    const u32* __restrict__ xp,        // [BATCH][TSEG][768] u32 (fp16 pairs), layer-1 xp
    const u32* __restrict__ whh,       // [2][G3][256] u32 (fp16 pairs)
    const u32* __restrict__ wih2,      // [G3][256] u32, layer-2 W_ih
    const float* __restrict__ bhh,     // [2*G3]
    const float* __restrict__ bih2,    // [G3]
    float* __restrict__ out,           // [BATCH][TLEN][HDIM] fp32
    u32* __restrict__ h1buf,           // [4][8192]
    u32* __restrict__ h2buf,           // [2][8192]
    u32* __restrict__ flags,           // [64]: L1 [0..15], L2 [32..47]
    int t0, int t1, int lgT)
{
  const int l2 = blockIdx.x >> 4;
  const int c  = blockIdx.x & 15;
  const int tid = threadIdx.x;
  const int lane = tid & 63;
  const int w = tid >> 6;
  const int l31 = lane & 31;
  const int kh = lane >> 5;

  __shared__ u32 st_l[32 * 260];    // own state (h1 for L1 / h2 for L2)
  __shared__ u32 h1_l[32 * 260];    // L2 only: h1 input
  __shared__ float sg_h[96 * 33];   // W_hh result
  __shared__ float sg_i[96 * 33];   // W_ih2 result (L2)

  // one MFMA tile per wave: waves 0-2 -> W_hh gate tiles; waves 3-5 (L2) -> W_ih2 tiles
  half8 bf[32];
  const bool mfma_w = (w < 3) || (l2 && w < 6);
  if (mfma_w) {
    const int gt = (w < 3) ? w : w - 3;
    const int grow = gt * 512 + c * 32 + l31;
    const u32* wsrc = (w < 3) ? (whh + (size_t)l2 * (G3 * 256)) : wih2;
#pragma unroll
    for (int ks = 0; ks < 32; ++ks)
      bf[ks] = *(const half8*)&wsrc[(size_t)grow * 256 + ks * 8 + kh * 4];
  }

  // epilogue mapping: thread -> group g = tid>>4, dim pair dp = tid&15 (global dims c*32+2dp, +1)
  const int dp = tid & 15;
  const int ga = tid >> 4;
  const float* bhh_l = bhh + l2 * G3;
  float biasH[3][2], biasI[3][2];
#pragma unroll
  for (int gt = 0; gt < 3; ++gt) {
    biasH[gt][0] = bhh_l[gt * 512 + c * 32 + 2 * dp];
    biasH[gt][1] = bhh_l[gt * 512 + c * 32 + 2 * dp + 1];
    biasI[gt][0] = l2 ? bih2[gt * 512 + c * 32 + 2 * dp] : 0.0f;
    biasI[gt][1] = l2 ? bih2[gt * 512 + c * 32 + 2 * dp + 1] : 0.0f;
  }

  for (int t = t0; t < t1; ++t) {
    // L1: prefetch xp for this step (overlaps peers' poll/barrier)
    u32 xu[3];
    if (!l2) {
      const size_t row = ((size_t)(ga << lgT) + (size_t)(t - t0)) * 768;
#pragma unroll
      for (int gt = 0; gt < 3; ++gt)
        xu[gt] = xp[row + gt * 256 + c * 16 + dp];
    }
    // wave 0 polls both flag lines; rest of block waits at B0
    if (w == 0) {
      const int n1 = l2 ? (t + 1) : t;
      const int n2 = l2 ? t       : (t - 3);
      const int fl = lane & 15;
      while (true) {
        const int f1 = (int)llc_load32(&flags[fl]);
        const int f2 = (int)llc_load32(&flags[32 + fl]);
        if (__all((int)((f1 >= n1) && (f2 >= n2)))) break;
        __builtin_amdgcn_s_sleep(1);
      }
    }
    __syncthreads();   // B0: quorum reached

    // load own state (32KB) -> LDS
    const u32* stsrc = l2 ? (h2buf + (size_t)(t & 1) * 8192)
                          : (h1buf + (size_t)(t & 3) * 8192);
#pragma unroll
    for (int j = 0; j < 16; ++j) {
      const int i = j * 512 + tid;
      st_l[(i >> 8) * 260 + (i & 255)] = llc_load32(&stsrc[i]);
    }
    if (l2) {
      // h1 version t+1 (L1's output at step t) lives in slot (t+1)&3
      const u32* h1src = h1buf + (size_t)((t + 1) & 3) * 8192;
#pragma unroll
      for (int j = 0; j < 16; ++j) {
        const int i = j * 512 + tid;
        h1_l[(i >> 8) * 260 + (i & 255)] = llc_load32(&h1src[i]);
      }
    }
    __syncthreads();   // B1

    const u32 hpp = st_l[ga * 260 + c * 16 + dp];

    if (mfma_w) {
      f32x16 acc;
#pragma unroll
      for (int i = 0; i < 16; ++i) acc[i] = 0.0f;
      const u32* asrc = (w < 3) ? st_l : h1_l;
#pragma unroll
      for (int ks = 0; ks < 32; ++ks) {
        const half8 af = *(const half8*)&asrc[l31 * 260 + ks * 8 + kh * 4];
        acc = __builtin_amdgcn_mfma_f32_32x32x16_f16(af, bf[ks], acc, 0, 0, 0);
      }
      // C/D map (verified): col=l31 -> local row, row=(r&3)+8*(r>>2)+4*kh -> group
      const int gt = (w < 3) ? w : w - 3;
      float* sg = (w < 3) ? sg_h : sg_i;
#pragma unroll
      for (int r = 0; r < 16; ++r) {
        const int grp = (r & 3) + 8 * (r >> 2) + 4 * kh;
        sg[(gt * 32 + l31) * 33 + grp] = acc[r];
      }
    }
    __syncthreads();   // B2

    // epilogue: one group x one dim-pair per thread
    float hn0, hn1;
    {
      const half2t hp2 = __builtin_bit_cast(half2t, hpp);
      float hn[2];
#pragma unroll
      for (int dd = 0; dd < 2; ++dd) {
        const int d = 2 * dp + dd;
        float xr, xz, xn;
        if (!l2) {
          const half2t xr2 = __builtin_bit_cast(half2t, xu[0]);
          const half2t xz2 = __builtin_bit_cast(half2t, xu[1]);
          const half2t xn2 = __builtin_bit_cast(half2t, xu[2]);
          xr = (float)(dd ? xr2.y : xr2.x);
          xz = (float)(dd ? xz2.y : xz2.x);
          xn = (float)(dd ? xn2.y : xn2.x);
        } else {
          xr = sg_i[(0 * 32 + d) * 33 + ga] + biasI[0][dd];
          xz = sg_i[(32 + d) * 33 + ga]     + biasI[1][dd];
          xn = sg_i[(64 + d) * 33 + ga]     + biasI[2][dd];
        }
        const float hprev = (float)(dd ? hp2.y : hp2.x);
        const float rr = fast_sigmoid(xr + sg_h[(0 * 32 + d) * 33 + ga] + biasH[0][dd]);
        const float zz = fast_sigmoid(xz + sg_h[(32 + d) * 33 + ga]     + biasH[1][dd]);
        const float nn = fast_tanh(xn + rr * (sg_h[(64 + d) * 33 + ga]  + biasH[2][dd]));
        hn[dd] = (1.0f - zz) * nn + zz * hprev;
      }
      hn0 = hn[0]; hn1 = hn[1];
      // h-state store only (fp32 out store deferred past the publish)
      if (!l2) {
        llc_store32(&h1buf[(size_t)((t + 1) & 3) * 8192 + ga * 256 + c * 16 + dp],
                    pack2h(hn0, hn1));
      } else {
        llc_store32(&h2buf[(size_t)((t + 1) & 1) * 8192 + ga * 256 + c * 16 + dp],
                    pack2h(hn0, hn1));
      }
    }
    // per-wave drain, block-wide rendezvous, ONE parallel flag store per block
    asm volatile("s_waitcnt vmcnt(0)" ::: "memory");
    __syncthreads();   // B3: all waves' h stores are at the coherence point
    if (tid == 0)
      llc_store32(&flags[l2 * 32 + c], (u32)(t + 1));
    // deferred output store (not on the critical sync path)
    if (l2) {
      float2 v; v.x = hn0; v.y = hn1;
      *(float2*)&out[((size_t)ga * TLEN + t) * HDIM + c * 32 + 2 * dp] = v;
    }
  }
}

// ---------------- host launcher ----------------
extern "C" void kernel_launch(void* const* d_in, const int* in_sizes, int n_in,
                              void* d_out, int out_size, void* d_ws, size_t ws_size,
                              hipStream_t stream)
{
  const float* x     = (const float*)d_in[0];
  const float* gamma = (const float*)d_in[1];
  const float* beta  = (const float*)d_in[2];
  const float* Wih   = (const float*)d_in[3];
  const float* Whh   = (const float*)d_in[4];
  const float* bih   = (const float*)d_in[5];
  const float* bhh   = (const float*)d_in[6];
  float* out = (float*)d_out;

  // ws layout: [xp: 32*TSEG*1536*2][hseq: 67MB][wih_h][whh_h][h1buf 4][h2buf 2][flags]
  const size_t wbytes  = (size_t)2 * G3 * HDIM * 2;                 // 3,145,728 each
  const size_t hseqb   = (size_t)BATCH * TLEN * HDIM * 2;           // 67,108,864
  const size_t fixed   = hseqb + 2 * wbytes + (size_t)6 * 8192 * 4 + 64 * 4 + 4096;
  int lgT = 11;
  while (lgT > 2 && ((size_t)BATCH * ((size_t)1 << lgT) * G3 * 2 + fixed) > ws_size) --lgT;
  const int TSEG = 1 << lgT;
  const int nseg = TLEN / TSEG;

  char* ws = (char*)d_ws;
  _Float16* xp    = (_Float16*)ws;
  char* base      = ws + (size_t)BATCH * TSEG * G3 * 2;
  _Float16* hseq  = (_Float16*)base;                                // LN output (fp16)
  _Float16* wih_h = (_Float16*)(base + hseqb);
  _Float16* whh_h = (_Float16*)(base + hseqb + wbytes);
  u32*      h1buf = (u32*)     (base + hseqb + 2 * wbytes);
  u32*      h2buf = h1buf + (size_t)4 * 8192;
  u32*      flags = h2buf + (size_t)2 * 8192;

  convert_weights<<<512, 256, 0, stream>>>(Wih, Whh, wih_h, whh_h);
  ln_kernel<<<BATCH * TLEN, 256, 0, stream>>>(x, gamma, beta, hseq);
  init_sync<<<192, 256, 0, stream>>>(h1buf, flags);

  const dim3 ggrid(BATCH * TSEG / 128, 12);
  for (int s = 0; s < nseg; ++s) {
    const int t0 = s * TSEG;
    gemm_f16<<<ggrid, 256, 0, stream>>>(hseq, wih_h, bih, xp, t0, lgT);
    gru_fused<<<32, 512, 0, stream>>>((const u32*)xp, (const u32*)whh_h,
                                      (const u32*)(wih_h + (size_t)G3 * HDIM),
                                      bhh, bih + G3, out,
                                      h1buf, h2buf, flags, t0, t0 + TSEG, lgT);
  }
}

// Round 9
// 9360.735 us; speedup vs baseline: 9.0810x; 1.9961x over previous
//
#include <hip/hip_runtime.h>
#include <hip/hip_fp16.h>

typedef float f32x4 __attribute__((ext_vector_type(4)));
typedef float f32x16 __attribute__((ext_vector_type(16)));
typedef _Float16 half8 __attribute__((ext_vector_type(8)));
typedef _Float16 half2t __attribute__((ext_vector_type(2)));
typedef unsigned int u32;
typedef u32 u32x4v __attribute__((ext_vector_type(4)));

#define DEVI static __device__ __forceinline__

constexpr int BATCH = 32;
constexpr int TLEN  = 2048;
constexpr int HDIM  = 512;
constexpr int G3    = 1536;   // 3*H

DEVI float fast_sigmoid(float x) { return 1.0f / (1.0f + __expf(-x)); }

DEVI float fast_tanh(float x) {
  const float ax = fabsf(x);
  const float t = __expf(-2.0f * ax);
  const float r = (1.0f - t) / (1.0f + t);
  return copysignf(r, x);
}

DEVI u32 pack2h(float a, float b) {
  return __builtin_bit_cast(u32, __builtin_amdgcn_cvt_pkrtz(a, b));
}

DEVI u32 llc_load32(const u32* p) {
  return __hip_atomic_load(p, __ATOMIC_RELAXED, __HIP_MEMORY_SCOPE_AGENT);
}
DEVI void llc_store32(u32* p, u32 v) {
  __hip_atomic_store(p, v, __ATOMIC_RELAXED, __HIP_MEMORY_SCOPE_AGENT);
}

// Issue a 16B coherence-point load (bypasses L1/L2 like an agent-scope atomic load,
// but vectorized). NO waitcnt inside: caller must drain vmcnt before using the result
// and fence with sched_barrier(0) (guide rule #18).
DEVI u32x4v llc_load128_async(const u32* p) {
  u32x4v r;
  asm volatile("global_load_dwordx4 %0, %1, off sc0 sc1" : "=&v"(r) : "v"(p));
  return r;
}

// ---------------- weight conversion (fp32 -> fp16) ----------------
__global__ void convert_weights(const float* __restrict__ wih, const float* __restrict__ whh,
                                _Float16* __restrict__ wih_h, _Float16* __restrict__ whh_h)
{
  const size_t n = (size_t)2 * G3 * HDIM;
  for (size_t i = (size_t)blockIdx.x * blockDim.x + threadIdx.x; i < n;
       i += (size_t)gridDim.x * blockDim.x) {
    wih_h[i] = (_Float16)wih[i];
    whh_h[i] = (_Float16)whh[i];
  }
}

// ---------------- layernorm: fp32 in -> fp16 out ----------------
__global__ __launch_bounds__(256) void ln_kernel(const float* __restrict__ x,
    const float* __restrict__ gamma, const float* __restrict__ beta,
    _Float16* __restrict__ out)
{
  const int row = blockIdx.x;
  const int tid = threadIdx.x;
  const float* xr = x + (size_t)row * HDIM;
  float a = xr[tid], b = xr[tid + 256];
  float s = a + b, ss = a * a + b * b;
#pragma unroll
  for (int m = 1; m < 64; m <<= 1) {
    s  += __shfl_xor(s, m, 64);
    ss += __shfl_xor(ss, m, 64);
  }
  __shared__ float sb[8];
  const int w = tid >> 6;
  if ((tid & 63) == 0) { sb[w] = s; sb[4 + w] = ss; }
  __syncthreads();
  s  = sb[0] + sb[1] + sb[2] + sb[3];
  ss = sb[4] + sb[5] + sb[6] + sb[7];
  const float mu   = s * (1.0f / HDIM);
  const float var  = ss * (1.0f / HDIM) - mu * mu;
  const float rstd = rsqrtf(var + 1e-5f);
  out[(size_t)row * HDIM + tid]       = (_Float16)((a - mu) * rstd * gamma[tid] + beta[tid]);
  out[(size_t)row * HDIM + tid + 256] = (_Float16)((b - mu) * rstd * gamma[tid + 256] + beta[tid + 256]);
}

// ---------------- fp16 MFMA GEMM: C[m,n] = sum_k A[m,k]*W[n,k] + bias[n] ----------------
__global__ __launch_bounds__(256) void gemm_f16(
    const _Float16* __restrict__ A, const _Float16* __restrict__ W,
    const float* __restrict__ bias, _Float16* __restrict__ C,
    int t0, int lgT)
{
  __shared__ _Float16 As[128][40];
  __shared__ _Float16 Bs[128][40];
  const int bm = blockIdx.x;
  const int bn = blockIdx.y;
  const int tid = threadIdx.x;
  const int lane = tid & 63;
  const int wv = tid >> 6;
  const int wm = wv >> 1, wn = wv & 1;
  const int l15 = lane & 15, g4 = lane >> 4;
  const int tmask = (1 << lgT) - 1;

  f32x4 zero4 = {0.f, 0.f, 0.f, 0.f};
  f32x4 acc[4][4];
#pragma unroll
  for (int i = 0; i < 4; ++i) {
#pragma unroll
    for (int j = 0; j < 4; ++j) acc[i][j] = zero4;
  }

  const int srow = tid >> 2;
  const int scol = (tid & 3) * 8;
  size_t arow[2];
#pragma unroll
  for (int r2 = 0; r2 < 2; ++r2) {
    int m = bm * 128 + r2 * 64 + srow;
    int b = m >> lgT, tt = m & tmask;
    arow[r2] = ((size_t)b * TLEN + (size_t)(t0 + tt)) * HDIM;
  }
  const size_t brow0 = (size_t)(bn * 128 + srow) * HDIM;

  for (int kt = 0; kt < HDIM; kt += 32) {
#pragma unroll
    for (int r2 = 0; r2 < 2; ++r2) {
      *(uint4*)&As[r2 * 64 + srow][scol] = *(const uint4*)&A[arow[r2] + kt + scol];
      *(uint4*)&Bs[r2 * 64 + srow][scol] = *(const uint4*)&W[brow0 + (size_t)r2 * 64 * HDIM + kt + scol];
    }
    __syncthreads();
    half8 af[4], bf[4];
#pragma unroll
    for (int i = 0; i < 4; ++i) af[i] = *(const half8*)&As[wm * 64 + i * 16 + l15][g4 * 8];
#pragma unroll
    for (int j = 0; j < 4; ++j) bf[j] = *(const half8*)&Bs[wn * 64 + j * 16 + l15][g4 * 8];
#pragma unroll
    for (int i = 0; i < 4; ++i) {
#pragma unroll
      for (int j = 0; j < 4; ++j)
        acc[i][j] = __builtin_amdgcn_mfma_f32_16x16x32_f16(af[i], bf[j], acc[i][j], 0, 0, 0);
    }
    __syncthreads();
  }
#pragma unroll
  for (int j = 0; j < 4; ++j) {
    const int col = bn * 128 + wn * 64 + j * 16 + l15;
    const float bi = bias[col];
#pragma unroll
    for (int i = 0; i < 4; ++i) {
      const int mrow = bm * 128 + wm * 64 + i * 16 + g4 * 4;
#pragma unroll
      for (int r = 0; r < 4; ++r)
        C[(size_t)(mrow + r) * G3 + col] = (_Float16)(acc[i][j][r] + bi);
    }
  }
}

// ---------------- sync-state init ----------------
__global__ void init_sync(u32* __restrict__ hbufs, u32* __restrict__ flags)
{
  const int i = blockIdx.x * 256 + threadIdx.x;
  if (i < 6 * 8192) hbufs[i] = 0u;   // h1buf[4 slots] + h2buf[2 slots], fp16 pairs (0,0)
  if (i < 64) flags[i] = 0u;         // L1 flags [0..15], L2 flags [32..47]
}

// ---------------- fused 2-layer persistent GRU recurrence ----------------
// 32 blocks: layer = bid>>4 (0: L1, 1: L2), c = bid&15 owns dims [c*32, c*32+32).
// Sync: 16 per-block flag words per layer (one cacheline each, parallel plain stores).
// Wave 0 polls both lines; barrier releases the block. Publish: per-wave vmcnt drain
// + barrier, then tid0 stores flag = t+1.
// h reload: vectorized coherence-point loads (dwordx4 sc0 sc1), ALL in flight, one drain.
// L1@t waits {L1 flags >= t, L2 flags >= t-3}; L2@t waits {L1 >= t+1, L2 >= t}.
__global__ __launch_bounds__(512, 1) void gru_fused(
    const u32* __restrict__ xp,        // [BATCH][TSEG][768] u32 (fp16 pairs), layer-1 xp
    const u32* __restrict__ whh,       // [2][G3][256] u32 (fp16 pairs)
    const u32* __restrict__ wih2,      // [G3][256] u32, layer-2 W_ih
    const float* __restrict__ bhh,     // [2*G3]
    const float* __restrict__ bih2,    // [G3]
    float* __restrict__ out,           // [BATCH][TLEN][HDIM] fp32
    u32* __restrict__ h1buf,           // [4][8192]
    u32* __restrict__ h2buf,           // [2][8192]
    u32* __restrict__ flags,           // [64]: L1 [0..15], L2 [32..47]
    int t0, int t1, int lgT)
{
  const int l2 = blockIdx.x >> 4;
  const int c  = blockIdx.x & 15;
  const int tid = threadIdx.x;
  const int lane = tid & 63;
  const int w = tid >> 6;
  const int l31 = lane & 31;
  const int kh = lane >> 5;

  __shared__ __align__(16) u32 st_l[32 * 260];    // own state (h1 for L1 / h2 for L2)
  __shared__ __align__(16) u32 h1_l[32 * 260];    // L2 only: h1 input
  __shared__ float sg_h[96 * 33];   // W_hh result
  __shared__ float sg_i[96 * 33];   // W_ih2 result (L2)

  // one MFMA tile per wave: waves 0-2 -> W_hh gate tiles; waves 3-5 (L2) -> W_ih2 tiles
  half8 bf[32];
  const bool mfma_w = (w < 3) || (l2 && w < 6);
  if (mfma_w) {
    const int gt = (w < 3) ? w : w - 3;
    const int grow = gt * 512 + c * 32 + l31;
    const u32* wsrc = (w < 3) ? (whh + (size_t)l2 * (G3 * 256)) : wih2;
#pragma unroll
    for (int ks = 0; ks < 32; ++ks)
      bf[ks] = *(const half8*)&wsrc[(size_t)grow * 256 + ks * 8 + kh * 4];
  }

  // epilogue mapping: thread -> group g = tid>>4, dim pair dp = tid&15 (global dims c*32+2dp, +1)
  const int dp = tid & 15;
  const int ga = tid >> 4;
  const float* bhh_l = bhh + l2 * G3;
  float biasH[3][2], biasI[3][2];
#pragma unroll
  for (int gt = 0; gt < 3; ++gt) {
    biasH[gt][0] = bhh_l[gt * 512 + c * 32 + 2 * dp];
    biasH[gt][1] = bhh_l[gt * 512 + c * 32 + 2 * dp + 1];
    biasI[gt][0] = l2 ? bih2[gt * 512 + c * 32 + 2 * dp] : 0.0f;
    biasI[gt][1] = l2 ? bih2[gt * 512 + c * 32 + 2 * dp + 1] : 0.0f;
  }

  for (int t = t0; t < t1; ++t) {
    // L1: prefetch xp for this step (overlaps peers' poll/barrier)
    u32 xu[3];
    if (!l2) {
      const size_t row = ((size_t)(ga << lgT) + (size_t)(t - t0)) * 768;
#pragma unroll
      for (int gt = 0; gt < 3; ++gt)
        xu[gt] = xp[row + gt * 256 + c * 16 + dp];
    }
    // wave 0 polls both flag lines; rest of block waits at B0
    if (w == 0) {
      const int n1 = l2 ? (t + 1) : t;
      const int n2 = l2 ? t       : (t - 3);
      const int fl = lane & 15;
      while (true) {
        const int f1 = (int)llc_load32(&flags[fl]);
        const int f2 = (int)llc_load32(&flags[32 + fl]);
        if (__all((int)((f1 >= n1) && (f2 >= n2)))) break;
        __builtin_amdgcn_s_sleep(1);
      }
    }
    __syncthreads();   // B0: quorum reached

    // h reload: 4 (L1) / 8 (L2) dwordx4 coherence-point loads per thread, all in
    // flight, ONE drain, then 16B LDS writes.
    const u32* stsrc = l2 ? (h2buf + (size_t)(t & 1) * 8192)
                          : (h1buf + (size_t)(t & 3) * 8192);
    u32x4v sv0, sv1, sv2, sv3, hv0, hv1, hv2, hv3;
    {
      const u32* sp = stsrc + (tid << 2);
      sv0 = llc_load128_async(sp);
      sv1 = llc_load128_async(sp + 2048);
      sv2 = llc_load128_async(sp + 4096);
      sv3 = llc_load128_async(sp + 6144);
      if (l2) {
        // h1 version t+1 (L1's output at step t) lives in slot (t+1)&3
        const u32* hp = h1buf + (size_t)((t + 1) & 3) * 8192 + (tid << 2);
        hv0 = llc_load128_async(hp);
        hv1 = llc_load128_async(hp + 2048);
        hv2 = llc_load128_async(hp + 4096);
        hv3 = llc_load128_async(hp + 6144);
      }
    }
    asm volatile("s_waitcnt vmcnt(0)" ::: "memory");
    __builtin_amdgcn_sched_barrier(0);
    {
      const int r0 = tid >> 6;              // row within 8-row chunk
      const int cc = (tid << 2) & 255;      // u32 col
      *(u32x4v*)&st_l[(0  + r0) * 260 + cc] = sv0;
      *(u32x4v*)&st_l[(8  + r0) * 260 + cc] = sv1;
      *(u32x4v*)&st_l[(16 + r0) * 260 + cc] = sv2;
      *(u32x4v*)&st_l[(24 + r0) * 260 + cc] = sv3;
      if (l2) {
        *(u32x4v*)&h1_l[(0  + r0) * 260 + cc] = hv0;
        *(u32x4v*)&h1_l[(8  + r0) * 260 + cc] = hv1;
        *(u32x4v*)&h1_l[(16 + r0) * 260 + cc] = hv2;
        *(u32x4v*)&h1_l[(24 + r0) * 260 + cc] = hv3;
      }
    }
    __syncthreads();   // B1

    const u32 hpp = st_l[ga * 260 + c * 16 + dp];

    if (mfma_w) {
      f32x16 acc;
#pragma unroll
      for (int i = 0; i < 16; ++i) acc[i] = 0.0f;
      const u32* asrc = (w < 3) ? st_l : h1_l;
#pragma unroll
      for (int ks = 0; ks < 32; ++ks) {
        const half8 af = *(const half8*)&asrc[l31 * 260 + ks * 8 + kh * 4];
        acc = __builtin_amdgcn_mfma_f32_32x32x16_f16(af, bf[ks], acc, 0, 0, 0);
      }
      // C/D map (verified): col=l31 -> local row, row=(r&3)+8*(r>>2)+4*kh -> group
      const int gt = (w < 3) ? w : w - 3;
      float* sg = (w < 3) ? sg_h : sg_i;
#pragma unroll
      for (int r = 0; r < 16; ++r) {
        const int grp = (r & 3) + 8 * (r >> 2) + 4 * kh;
        sg[(gt * 32 + l31) * 33 + grp] = acc[r];
      }
    }
    __syncthreads();   // B2

    // epilogue: one group x one dim-pair per thread
    float hn0, hn1;
    {
      const half2t hp2 = __builtin_bit_cast(half2t, hpp);
      float hn[2];
#pragma unroll
      for (int dd = 0; dd < 2; ++dd) {
        const int d = 2 * dp + dd;
        float xr, xz, xn;
        if (!l2) {
          const half2t xr2 = __builtin_bit_cast(half2t, xu[0]);
          const half2t xz2 = __builtin_bit_cast(half2t, xu[1]);
          const half2t xn2 = __builtin_bit_cast(half2t, xu[2]);
          xr = (float)(dd ? xr2.y : xr2.x);
          xz = (float)(dd ? xz2.y : xz2.x);
          xn = (float)(dd ? xn2.y : xn2.x);
        } else {
          xr = sg_i[(0 * 32 + d) * 33 + ga] + biasI[0][dd];
          xz = sg_i[(32 + d) * 33 + ga]     + biasI[1][dd];
          xn = sg_i[(64 + d) * 33 + ga]     + biasI[2][dd];
        }
        const float hprev = (float)(dd ? hp2.y : hp2.x);
        const float rr = fast_sigmoid(xr + sg_h[(0 * 32 + d) * 33 + ga] + biasH[0][dd]);
        const float zz = fast_sigmoid(xz + sg_h[(32 + d) * 33 + ga]     + biasH[1][dd]);
        const float nn = fast_tanh(xn + rr * (sg_h[(64 + d) * 33 + ga]  + biasH[2][dd]));
        hn[dd] = (1.0f - zz) * nn + zz * hprev;
      }
      hn0 = hn[0]; hn1 = hn[1];
      // h-state store only (fp32 out store deferred past the publish)
      if (!l2) {
        llc_store32(&h1buf[(size_t)((t + 1) & 3) * 8192 + ga * 256 + c * 16 + dp],
                    pack2h(hn0, hn1));
      } else {
        llc_store32(&h2buf[(size_t)((t + 1) & 1) * 8192 + ga * 256 + c * 16 + dp],
                    pack2h(hn0, hn1));
      }
    }
    // per-wave drain, block-wide rendezvous, ONE parallel flag store per block
    asm volatile("s_waitcnt vmcnt(0)" ::: "memory");
    __syncthreads();   // B3: all waves' h stores are at the coherence point
    if (tid == 0)
      llc_store32(&flags[l2 * 32 + c], (u32)(t + 1));
    // deferred output store (not on the critical sync path)
    if (l2) {
      float2 v; v.x = hn0; v.y = hn1;
      *(float2*)&out[((size_t)ga * TLEN + t) * HDIM + c * 32 + 2 * dp] = v;
    }
  }
}

// ---------------- host launcher ----------------
extern "C" void kernel_launch(void* const* d_in, const int* in_sizes, int n_in,
                              void* d_out, int out_size, void* d_ws, size_t ws_size,
                              hipStream_t stream)
{
  const float* x     = (const float*)d_in[0];
  const float* gamma = (const float*)d_in[1];
  const float* beta  = (const float*)d_in[2];
  const float* Wih   = (const float*)d_in[3];
  const float* Whh   = (const float*)d_in[4];
  const float* bih   = (const float*)d_in[5];
  const float* bhh   = (const float*)d_in[6];
  float* out = (float*)d_out;

  // ws layout: [xp: 32*TSEG*1536*2][hseq: 67MB][wih_h][whh_h][h1buf 4][h2buf 2][flags]
  const size_t wbytes  = (size_t)2 * G3 * HDIM * 2;                 // 3,145,728 each
  const size_t hseqb   = (size_t)BATCH * TLEN * HDIM * 2;           // 67,108,864
  const size_t fixed   = hseqb + 2 * wbytes + (size_t)6 * 8192 * 4 + 64 * 4 + 4096;
  int lgT = 11;
  while (lgT > 2 && ((size_t)BATCH * ((size_t)1 << lgT) * G3 * 2 + fixed) > ws_size) --lgT;
  const int TSEG = 1 << lgT;
  const int nseg = TLEN / TSEG;

  char* ws = (char*)d_ws;
  _Float16* xp    = (_Float16*)ws;
  char* base      = ws + (size_t)BATCH * TSEG * G3 * 2;
  _Float16* hseq  = (_Float16*)base;                                // LN output (fp16)
  _Float16* wih_h = (_Float16*)(base + hseqb);
  _Float16* whh_h = (_Float16*)(base + hseqb + wbytes);
  u32*      h1buf = (u32*)     (base + hseqb + 2 * wbytes);
  u32*      h2buf = h1buf + (size_t)4 * 8192;
  u32*      flags = h2buf + (size_t)2 * 8192;

  convert_weights<<<512, 256, 0, stream>>>(Wih, Whh, wih_h, whh_h);
  ln_kernel<<<BATCH * TLEN, 256, 0, stream>>>(x, gamma, beta, hseq);
  init_sync<<<192, 256, 0, stream>>>(h1buf, flags);

  const dim3 ggrid(BATCH * TSEG / 128, 12);
  for (int s = 0; s < nseg; ++s) {
    const int t0 = s * TSEG;
    gemm_f16<<<ggrid, 256, 0, stream>>>(hseq, wih_h, bih, xp, t0, lgT);
    gru_fused<<<32, 512, 0, stream>>>((const u32*)xp, (const u32*)whh_h,
                                      (const u32*)(wih_h + (size_t)G3 * HDIM),
                                      bhh, bih + G3, out,
                                      h1buf, h2buf, flags, t0, t0 + TSEG, lgT);
  }
}

// Round 10
// 8701.213 us; speedup vs baseline: 9.7693x; 1.0758x over previous
//
#include <hip/hip_runtime.h>
#include <hip/hip_fp16.h>

typedef float f32x4 __attribute__((ext_vector_type(4)));
typedef float f32x16 __attribute__((ext_vector_type(16)));
typedef _Float16 half8 __attribute__((ext_vector_type(8)));
typedef _Float16 half2t __attribute__((ext_vector_type(2)));
typedef unsigned int u32;
typedef u32 u32x4v __attribute__((ext_vector_type(4)));

#define DEVI static __device__ __forceinline__

constexpr int BATCH = 32;
constexpr int TLEN  = 2048;
constexpr int HDIM  = 512;
constexpr int G3    = 1536;   // 3*H
constexpr u32 POIS  = 0xFFFFFFFFu;   // (NaN,NaN) fp16 pair — unreachable: |h|<=1 always
constexpr int NSLOT = 16;            // h ring depth (slot = step % 16)

DEVI float fast_sigmoid(float x) { return 1.0f / (1.0f + __expf(-x)); }

DEVI float fast_tanh(float x) {
  const float ax = fabsf(x);
  const float t = __expf(-2.0f * ax);
  const float r = (1.0f - t) / (1.0f + t);
  return copysignf(r, x);
}

DEVI u32 pack2h(float a, float b) {
  return __builtin_bit_cast(u32, __builtin_amdgcn_cvt_pkrtz(a, b));
}

DEVI u32 llc_load32(const u32* p) {
  return __hip_atomic_load(p, __ATOMIC_RELAXED, __HIP_MEMORY_SCOPE_AGENT);
}
DEVI void llc_store32(u32* p, u32 v) {
  __hip_atomic_store(p, v, __ATOMIC_RELAXED, __HIP_MEMORY_SCOPE_AGENT);
}

// 16B coherence-point load (bypasses L1/L2, like agent-scope atomic). NO waitcnt
// inside: caller drains vmcnt and fences with sched_barrier(0) (guide rule #18).
DEVI u32x4v llc_load128_async(const u32* p) {
  u32x4v r;
  asm volatile("global_load_dwordx4 %0, %1, off sc0 sc1" : "=&v"(r) : "v"(p));
  return r;
}

DEVI int chk4(u32x4v v) {
  return (int)((v[0] == POIS) | (v[1] == POIS) | (v[2] == POIS) | (v[3] == POIS));
}

// ---------------- weight conversion (fp32 -> fp16) ----------------
__global__ void convert_weights(const float* __restrict__ wih, const float* __restrict__ whh,
                                _Float16* __restrict__ wih_h, _Float16* __restrict__ whh_h)
{
  const size_t n = (size_t)2 * G3 * HDIM;
  for (size_t i = (size_t)blockIdx.x * blockDim.x + threadIdx.x; i < n;
       i += (size_t)gridDim.x * blockDim.x) {
    wih_h[i] = (_Float16)wih[i];
    whh_h[i] = (_Float16)whh[i];
  }
}

// ---------------- layernorm: fp32 in -> fp16 out ----------------
__global__ __launch_bounds__(256) void ln_kernel(const float* __restrict__ x,
    const float* __restrict__ gamma, const float* __restrict__ beta,
    _Float16* __restrict__ out)
{
  const int row = blockIdx.x;
  const int tid = threadIdx.x;
  const float* xr = x + (size_t)row * HDIM;
  float a = xr[tid], b = xr[tid + 256];
  float s = a + b, ss = a * a + b * b;
#pragma unroll
  for (int m = 1; m < 64; m <<= 1) {
    s  += __shfl_xor(s, m, 64);
    ss += __shfl_xor(ss, m, 64);
  }
  __shared__ float sb[8];
  const int w = tid >> 6;
  if ((tid & 63) == 0) { sb[w] = s; sb[4 + w] = ss; }
  __syncthreads();
  s  = sb[0] + sb[1] + sb[2] + sb[3];
  ss = sb[4] + sb[5] + sb[6] + sb[7];
  const float mu   = s * (1.0f / HDIM);
  const float var  = ss * (1.0f / HDIM) - mu * mu;
  const float rstd = rsqrtf(var + 1e-5f);
  out[(size_t)row * HDIM + tid]       = (_Float16)((a - mu) * rstd * gamma[tid] + beta[tid]);
  out[(size_t)row * HDIM + tid + 256] = (_Float16)((b - mu) * rstd * gamma[tid + 256] + beta[tid + 256]);
}

// ---------------- fp16 MFMA GEMM: C[m,n] = sum_k A[m,k]*W[n,k] + bias[n] ----------------
__global__ __launch_bounds__(256) void gemm_f16(
    const _Float16* __restrict__ A, const _Float16* __restrict__ W,
    const float* __restrict__ bias, _Float16* __restrict__ C,
    int t0, int lgT)
{
  __shared__ _Float16 As[128][40];
  __shared__ _Float16 Bs[128][40];
  const int bm = blockIdx.x;
  const int bn = blockIdx.y;
  const int tid = threadIdx.x;
  const int lane = tid & 63;
  const int wv = tid >> 6;
  const int wm = wv >> 1, wn = wv & 1;
  const int l15 = lane & 15, g4 = lane >> 4;
  const int tmask = (1 << lgT) - 1;

  f32x4 zero4 = {0.f, 0.f, 0.f, 0.f};
  f32x4 acc[4][4];
#pragma unroll
  for (int i = 0; i < 4; ++i) {
#pragma unroll
    for (int j = 0; j < 4; ++j) acc[i][j] = zero4;
  }

  const int srow = tid >> 2;
  const int scol = (tid & 3) * 8;
  size_t arow[2];
#pragma unroll
  for (int r2 = 0; r2 < 2; ++r2) {
    int m = bm * 128 + r2 * 64 + srow;
    int b = m >> lgT, tt = m & tmask;
    arow[r2] = ((size_t)b * TLEN + (size_t)(t0 + tt)) * HDIM;
  }
  const size_t brow0 = (size_t)(bn * 128 + srow) * HDIM;

  for (int kt = 0; kt < HDIM; kt += 32) {
#pragma unroll
    for (int r2 = 0; r2 < 2; ++r2) {
      *(uint4*)&As[r2 * 64 + srow][scol] = *(const uint4*)&A[arow[r2] + kt + scol];
      *(uint4*)&Bs[r2 * 64 + srow][scol] = *(const uint4*)&W[brow0 + (size_t)r2 * 64 * HDIM + kt + scol];
    }
    __syncthreads();
    half8 af[4], bf[4];
#pragma unroll
    for (int i = 0; i < 4; ++i) af[i] = *(const half8*)&As[wm * 64 + i * 16 + l15][g4 * 8];
#pragma unroll
    for (int j = 0; j < 4; ++j) bf[j] = *(const half8*)&Bs[wn * 64 + j * 16 + l15][g4 * 8];
#pragma unroll
    for (int i = 0; i < 4; ++i) {
#pragma unroll
      for (int j = 0; j < 4; ++j)
        acc[i][j] = __builtin_amdgcn_mfma_f32_16x16x32_f16(af[i], bf[j], acc[i][j], 0, 0, 0);
    }
    __syncthreads();
  }
#pragma unroll
  for (int j = 0; j < 4; ++j) {
    const int col = bn * 128 + wn * 64 + j * 16 + l15;
    const float bi = bias[col];
#pragma unroll
    for (int i = 0; i < 4; ++i) {
      const int mrow = bm * 128 + wm * 64 + i * 16 + g4 * 4;
#pragma unroll
      for (int r = 0; r < 4; ++r)
        C[(size_t)(mrow + r) * G3 + col] = (_Float16)(acc[i][j][r] + bi);
    }
  }
}

// ---------------- ring init: slot 0 = zeros (h_0), slots 1..15 = POISON ----------------
__global__ void init_sync(u32* __restrict__ h1ring, u32* __restrict__ h2ring,
                          u32* __restrict__ syncw)
{
  const int i = blockIdx.x * 256 + threadIdx.x;   // 0 .. 16*8192-1
  const u32 v = (i >> 13) == 0 ? 0u : POIS;
  h1ring[i] = v;
  h2ring[i] = v;
  if (i == 0) syncw[0] = 0u;
}

// ---------------- fused 2-layer persistent GRU recurrence (poison-ring sync) --------
// 32 blocks: layer = bid>>4, c = bid&15 owns dims [c*32, c*32+32).
// h exchange: 16-slot rings keyed by absolute step (slot = t%16). Consumers poll the
// DATA (per-wave, dwordx4 sc0 sc1) until no word == POISON — detection IS the reload.
// Producers: plain agent stores, NO drain/flag/barrier. Each block re-poisons its own
// region of slot (t+9)%16 after step t (next poll's vmcnt(0) drains the poison ahead
// of that slot's write at t+8). Back-pressure: L1 gates on L2 progress word >= t-3.
__global__ __launch_bounds__(512, 1) void gru_fused(
    const u32* __restrict__ xp,        // [BATCH][TSEG][768] u32 (fp16 pairs), layer-1 xp
    const u32* __restrict__ whh,       // [2][G3][256] u32 (fp16 pairs)
    const u32* __restrict__ wih2,      // [G3][256] u32, layer-2 W_ih
    const float* __restrict__ bhh,     // [2*G3]
    const float* __restrict__ bih2,    // [G3]
    float* __restrict__ out,           // [BATCH][TLEN][HDIM] fp32
    u32* __restrict__ h1ring,          // [16][8192]
    u32* __restrict__ h2ring,          // [16][8192]
    u32* __restrict__ syncw,           // [32]: [0] = L2 progress
    int t0, int t1, int lgT)
{
  const int l2 = blockIdx.x >> 4;
  const int c  = blockIdx.x & 15;
  const int tid = threadIdx.x;
  const int lane = tid & 63;
  const int w = tid >> 6;
  const int l31 = lane & 31;
  const int kh = lane >> 5;

  __shared__ __align__(16) u32 st_l[32 * 260];    // own state (h1 for L1 / h2 for L2)
  __shared__ __align__(16) u32 h1_l[32 * 260];    // L2 only: h1 input
  __shared__ float sg_h[96 * 33];   // W_hh result
  __shared__ float sg_i[96 * 33];   // W_ih2 result (L2)

  // one MFMA tile per wave: waves 0-2 -> W_hh gate tiles; waves 3-5 (L2) -> W_ih2 tiles
  half8 bf[32];
  const bool mfma_w = (w < 3) || (l2 && w < 6);
  if (mfma_w) {
    const int gt = (w < 3) ? w : w - 3;
    const int grow = gt * 512 + c * 32 + l31;
    const u32* wsrc = (w < 3) ? (whh + (size_t)l2 * (G3 * 256)) : wih2;
#pragma unroll
    for (int ks = 0; ks < 32; ++ks)
      bf[ks] = *(const half8*)&wsrc[(size_t)grow * 256 + ks * 8 + kh * 4];
  }

  // epilogue mapping: thread -> group ga = tid>>4, dim pair dp = tid&15
  const int dp = tid & 15;
  const int ga = tid >> 4;
  const float* bhh_l = bhh + l2 * G3;
  float biasH[3][2], biasI[3][2];
#pragma unroll
  for (int gt = 0; gt < 3; ++gt) {
    biasH[gt][0] = bhh_l[gt * 512 + c * 32 + 2 * dp];
    biasH[gt][1] = bhh_l[gt * 512 + c * 32 + 2 * dp + 1];
    biasI[gt][0] = l2 ? bih2[gt * 512 + c * 32 + 2 * dp] : 0.0f;
    biasI[gt][1] = l2 ? bih2[gt * 512 + c * 32 + 2 * dp + 1] : 0.0f;
  }

  u32* const ringOwn = l2 ? h2ring : h1ring;

  for (int t = t0; t < t1; ++t) {
    // L1: prefetch xp for this step (drained by the poll's vmcnt(0))
    u32 xu[3];
    if (!l2) {
      const size_t row = ((size_t)(ga << lgT) + (size_t)(t - t0)) * 768;
#pragma unroll
      for (int gt = 0; gt < 3; ++gt)
        xu[gt] = xp[row + gt * 256 + c * 16 + dp];
    }

    // poison-poll: per-wave, the data loads ARE the detection
    const u32* rdA = ringOwn + (size_t)(t & 15) * 8192 + (tid << 2);
    const u32* rdB = h1ring + (size_t)((t + 1) & 15) * 8192 + (tid << 2);
    u32x4v a0, a1, a2, a3, b0, b1, b2, b3;
    while (true) {
      a0 = llc_load128_async(rdA);
      a1 = llc_load128_async(rdA + 2048);
      a2 = llc_load128_async(rdA + 4096);
      a3 = llc_load128_async(rdA + 6144);
      if (l2) {
        b0 = llc_load128_async(rdB);
        b1 = llc_load128_async(rdB + 2048);
        b2 = llc_load128_async(rdB + 4096);
        b3 = llc_load128_async(rdB + 6144);
      }
      u32 prog = 0;
      if (!l2) prog = llc_load32(&syncw[0]);
      asm volatile("s_waitcnt vmcnt(0)" ::: "memory");
      __builtin_amdgcn_sched_barrier(0);
      int bad = chk4(a0) | chk4(a1) | chk4(a2) | chk4(a3);
      if (l2) bad |= chk4(b0) | chk4(b1) | chk4(b2) | chk4(b3);
      else    bad |= (int)((int)prog < t - 3);
      if (!__any(bad)) break;
      __builtin_amdgcn_s_sleep(1);
    }
    // wave writes its own units to LDS (no pre-barrier needed: per-wave poll)
    {
      const int r0 = tid >> 6;              // row within 8-row chunk
      const int cc = (tid << 2) & 255;      // u32 col
      *(u32x4v*)&st_l[(0  + r0) * 260 + cc] = a0;
      *(u32x4v*)&st_l[(8  + r0) * 260 + cc] = a1;
      *(u32x4v*)&st_l[(16 + r0) * 260 + cc] = a2;
      *(u32x4v*)&st_l[(24 + r0) * 260 + cc] = a3;
      if (l2) {
        *(u32x4v*)&h1_l[(0  + r0) * 260 + cc] = b0;
        *(u32x4v*)&h1_l[(8  + r0) * 260 + cc] = b1;
        *(u32x4v*)&h1_l[(16 + r0) * 260 + cc] = b2;
        *(u32x4v*)&h1_l[(24 + r0) * 260 + cc] = b3;
      }
    }
    __syncthreads();   // B1

    const u32 hpp = st_l[ga * 260 + c * 16 + dp];

    if (mfma_w) {
      f32x16 acc;
#pragma unroll
      for (int i = 0; i < 16; ++i) acc[i] = 0.0f;
      const u32* asrc = (w < 3) ? st_l : h1_l;
#pragma unroll
      for (int ks = 0; ks < 32; ++ks) {
        const half8 af = *(const half8*)&asrc[l31 * 260 + ks * 8 + kh * 4];
        acc = __builtin_amdgcn_mfma_f32_32x32x16_f16(af, bf[ks], acc, 0, 0, 0);
      }
      // C/D map (verified): col=l31 -> local row, row=(r&3)+8*(r>>2)+4*kh -> group
      const int gt = (w < 3) ? w : w - 3;
      float* sg = (w < 3) ? sg_h : sg_i;
#pragma unroll
      for (int r = 0; r < 16; ++r) {
        const int grp = (r & 3) + 8 * (r >> 2) + 4 * kh;
        sg[(gt * 32 + l31) * 33 + grp] = acc[r];
      }
    }
    __syncthreads();   // B2

    // epilogue: one group x one dim-pair per thread
    float hn0, hn1;
    {
      const half2t hp2 = __builtin_bit_cast(half2t, hpp);
      float hn[2];
#pragma unroll
      for (int dd = 0; dd < 2; ++dd) {
        const int d = 2 * dp + dd;
        float xr, xz, xn;
        if (!l2) {
          const half2t xr2 = __builtin_bit_cast(half2t, xu[0]);
          const half2t xz2 = __builtin_bit_cast(half2t, xu[1]);
          const half2t xn2 = __builtin_bit_cast(half2t, xu[2]);
          xr = (float)(dd ? xr2.y : xr2.x);
          xz = (float)(dd ? xz2.y : xz2.x);
          xn = (float)(dd ? xn2.y : xn2.x);
        } else {
          xr = sg_i[(0 * 32 + d) * 33 + ga] + biasI[0][dd];
          xz = sg_i[(32 + d) * 33 + ga]     + biasI[1][dd];
          xn = sg_i[(64 + d) * 33 + ga]     + biasI[2][dd];
        }
        const float hprev = (float)(dd ? hp2.y : hp2.x);
        const float rr = fast_sigmoid(xr + sg_h[(0 * 32 + d) * 33 + ga] + biasH[0][dd]);
        const float zz = fast_sigmoid(xz + sg_h[(32 + d) * 33 + ga]     + biasH[1][dd]);
        const float nn = fast_tanh(xn + rr * (sg_h[(64 + d) * 33 + ga]  + biasH[2][dd]));
        hn[dd] = (1.0f - zz) * nn + zz * hprev;
      }
      hn0 = hn[0]; hn1 = hn[1];
    }
    const int my = ga * 256 + c * 16 + dp;   // this thread's u32 slot in an 8192-word ring slot
    // publish h_{t+1} (no drain, no flag — consumers detect via poison clearing)
    llc_store32(&ringOwn[(size_t)((t + 1) & 15) * 8192 + my], pack2h(hn0, hn1));
    // deferred fp32 output store (off the sync path)
    if (l2) {
      float2 v; v.x = hn0; v.y = hn1;
      *(float2*)&out[((size_t)ga * TLEN + t) * HDIM + c * 32 + 2 * dp] = v;
    }
    // re-poison own region of slot used at step t+8 (drained by next poll's vmcnt(0))
    llc_store32(&ringOwn[(size_t)((t + 9) & 15) * 8192 + my], POIS);
    // L2 progress (one block publishes; intra-layer skew <= 1)
    if (l2 && c == 0 && tid == 0) llc_store32(&syncw[0], (u32)(t + 1));
  }
}

// ---------------- host launcher ----------------
extern "C" void kernel_launch(void* const* d_in, const int* in_sizes, int n_in,
                              void* d_out, int out_size, void* d_ws, size_t ws_size,
                              hipStream_t stream)
{
  const float* x     = (const float*)d_in[0];
  const float* gamma = (const float*)d_in[1];
  const float* beta  = (const float*)d_in[2];
  const float* Wih   = (const float*)d_in[3];
  const float* Whh   = (const float*)d_in[4];
  const float* bih   = (const float*)d_in[5];
  const float* bhh   = (const float*)d_in[6];
  float* out = (float*)d_out;

  // ws layout: [xp][hseq 67MB][wih_h][whh_h][h1ring][h2ring][syncw]
  const size_t wbytes  = (size_t)2 * G3 * HDIM * 2;                 // 3,145,728 each
  const size_t hseqb   = (size_t)BATCH * TLEN * HDIM * 2;           // 67,108,864
  const size_t ringb   = (size_t)NSLOT * 8192 * 4;                  // 524,288 each
  const size_t fixed   = hseqb + 2 * wbytes + 2 * ringb + 4096;
  int lgT = 11;
  while (lgT > 2 && ((size_t)BATCH * ((size_t)1 << lgT) * G3 * 2 + fixed) > ws_size) --lgT;
  const int TSEG = 1 << lgT;
  const int nseg = TLEN / TSEG;

  char* ws = (char*)d_ws;
  _Float16* xp     = (_Float16*)ws;
  char* base       = ws + (size_t)BATCH * TSEG * G3 * 2;
  _Float16* hseq   = (_Float16*)base;                               // LN output (fp16)
  _Float16* wih_h  = (_Float16*)(base + hseqb);
  _Float16* whh_h  = (_Float16*)(base + hseqb + wbytes);
  u32*      h1ring = (u32*)    (base + hseqb + 2 * wbytes);
  u32*      h2ring = h1ring + (size_t)NSLOT * 8192;
  u32*      syncw  = h2ring + (size_t)NSLOT * 8192;

  convert_weights<<<512, 256, 0, stream>>>(Wih, Whh, wih_h, whh_h);
  ln_kernel<<<BATCH * TLEN, 256, 0, stream>>>(x, gamma, beta, hseq);
  init_sync<<<512, 256, 0, stream>>>(h1ring, h2ring, syncw);

  const dim3 ggrid(BATCH * TSEG / 128, 12);
  for (int s = 0; s < nseg; ++s) {
    const int t0 = s * TSEG;
    gemm_f16<<<ggrid, 256, 0, stream>>>(hseq, wih_h, bih, xp, t0, lgT);
    gru_fused<<<32, 512, 0, stream>>>((const u32*)xp, (const u32*)whh_h,
                                      (const u32*)(wih_h + (size_t)G3 * HDIM),
                                      bhh, bih + G3, out,
                                      h1ring, h2ring, syncw, t0, t0 + TSEG, lgT);
  }
}